// Round 1
// baseline (1317.366 us; speedup 1.0000x reference)
//
#include <hip/hip_runtime.h>
#include <hip/hip_bf16.h>

#define N_NODES 50000
#define NUM_FEAT 2000
#define HEADS 8
#define HID 8
#define NUM_CLASSES 30
#define NUM_EDGES 1600000
#define E_TOTAL (NUM_EDGES + N_NODES)

// ---------------- GEMM: H[n][0:64] = x@w_res + b_res ; H[n][64:128] = x@w1 ----
// BM=64, BN=128, BK=16, 256 threads, 4x8 micro-tile per thread.
__global__ __launch_bounds__(256) void k_gemm(const float* __restrict__ X,
    const float* __restrict__ Wres, const float* __restrict__ W1,
    const float* __restrict__ brs, float* __restrict__ H) {
  constexpr int BM = 64, BN = 128, BK = 16;
  __shared__ float As[BK][BM];   // 4 KB, stored transposed (k-major)
  __shared__ float Bs[BK][BN];   // 8 KB
  const int tid = threadIdx.x;
  const int tx = tid & 15;       // 16 col groups
  const int ty = tid >> 4;       // 16 row groups
  const int m0 = blockIdx.x * BM;
  float acc[4][8] = {};

  // A staging: 64 rows x 16 k = 1024 elems = 256 float4; thread -> (row, kquad)
  const int ar = tid >> 2;            // 0..63
  const int ak = (tid & 3) * 4;       // 0,4,8,12

  for (int k0 = 0; k0 < NUM_FEAT; k0 += BK) {
    int row = m0 + ar; row = row < N_NODES ? row : N_NODES - 1;
    float4 av = *(const float4*)&X[(size_t)row * NUM_FEAT + k0 + ak];
    float4 bv[2];
#pragma unroll
    for (int i = 0; i < 2; ++i) {
      int q = tid + i * 256;
      int kb = q >> 5, col = (q & 31) * 4;
      const float* src = (col < 64) ? &Wres[(size_t)(k0 + kb) * 64 + col]
                                    : &W1[(size_t)(k0 + kb) * 64 + (col - 64)];
      bv[i] = *(const float4*)src;
    }
    __syncthreads();
    As[ak + 0][ar] = av.x; As[ak + 1][ar] = av.y;
    As[ak + 2][ar] = av.z; As[ak + 3][ar] = av.w;
#pragma unroll
    for (int i = 0; i < 2; ++i) {
      int q = tid + i * 256;
      int kb = q >> 5, col = (q & 31) * 4;
      *(float4*)&Bs[kb][col] = bv[i];
    }
    __syncthreads();
#pragma unroll
    for (int kk = 0; kk < BK; ++kk) {
      float4 a  = *(const float4*)&As[kk][ty * 4];
      float4 b0 = *(const float4*)&Bs[kk][tx * 4];
      float4 b1 = *(const float4*)&Bs[kk][tx * 4 + 64];
      float aa[4] = {a.x, a.y, a.z, a.w};
      float bb[8] = {b0.x, b0.y, b0.z, b0.w, b1.x, b1.y, b1.z, b1.w};
#pragma unroll
      for (int i = 0; i < 4; ++i)
#pragma unroll
        for (int j = 0; j < 8; ++j)
          acc[i][j] = fmaf(aa[i], bb[j], acc[i][j]);
    }
  }
#pragma unroll
  for (int i = 0; i < 4; ++i) {
    int row = m0 + ty * 4 + i;
    if (row >= N_NODES) continue;
    float4 o0 = make_float4(acc[i][0] + brs[tx * 4 + 0], acc[i][1] + brs[tx * 4 + 1],
                            acc[i][2] + brs[tx * 4 + 2], acc[i][3] + brs[tx * 4 + 3]);
    float4 o1 = make_float4(acc[i][4], acc[i][5], acc[i][6], acc[i][7]);
    *(float4*)&H[(size_t)row * 128 + tx * 4] = o0;
    *(float4*)&H[(size_t)row * 128 + 64 + tx * 4] = o1;
  }
}

// ---------------- per-node attention logits for layer 1 ---------------------
__global__ void k_attn1(const float* __restrict__ H, const float* __restrict__ att_src,
                        const float* __restrict__ att_dst, float* __restrict__ a_src,
                        float* __restrict__ a_dst) {
  int i = blockIdx.x * blockDim.x + threadIdx.x;  // i = n*8 + h
  if (i >= N_NODES * HEADS) return;
  int h = i & 7;
  const float* hp = &H[(size_t)(i >> 3) * 128 + 64 + h * 8];
  float s = 0.f, d = 0.f;
#pragma unroll
  for (int c = 0; c < 8; ++c) {
    float v = hp[c];
    s = fmaf(v, att_src[h * 8 + c], s);
    d = fmaf(v, att_dst[h * 8 + c], d);
  }
  a_src[i] = s; a_dst[i] = d;
}

// ---------------- CSR build (by dst) ----------------------------------------
__global__ void k_degree(const int* __restrict__ ei, int* __restrict__ deg) {
  int e = blockIdx.x * blockDim.x + threadIdx.x;
  if (e >= E_TOTAL) return;
  int d = e < NUM_EDGES ? ei[NUM_EDGES + e] : e - NUM_EDGES;
  atomicAdd(&deg[d], 1);
}

__global__ __launch_bounds__(1024) void k_scan(const int* __restrict__ deg,
                                               int* __restrict__ rowptr) {
  __shared__ int smem[1024];
  int t = threadIdx.x;
  int carry = 0;
  if (t == 0) rowptr[0] = 0;
  for (int base = 0; base < N_NODES; base += 1024) {
    int i = base + t;
    int v = (i < N_NODES) ? deg[i] : 0;
    smem[t] = v; __syncthreads();
    for (int off = 1; off < 1024; off <<= 1) {
      int add = (t >= off) ? smem[t - off] : 0;
      __syncthreads();
      smem[t] += add;
      __syncthreads();
    }
    int inc = smem[t];
    int tot = smem[1023];
    if (i < N_NODES) rowptr[i + 1] = carry + inc;
    carry += tot;
    __syncthreads();
  }
}

__global__ void k_fill(const int* __restrict__ ei, const int* __restrict__ rowptr,
                       int* __restrict__ cursor, int* __restrict__ eid) {
  int e = blockIdx.x * blockDim.x + threadIdx.x;
  if (e >= E_TOTAL) return;
  int d = e < NUM_EDGES ? ei[NUM_EDGES + e] : e - NUM_EDGES;
  int pos = atomicAdd(&cursor[d], 1);
  eid[rowptr[d] + pos] = e;
}

// ---------------- layer-1 aggregation: one wave per node, lane = (head*8+c) --
__global__ __launch_bounds__(256) void k_layer1(const int* __restrict__ ei,
    const int* __restrict__ rowptr, const int* __restrict__ eid,
    const float* __restrict__ H, const float* __restrict__ a_src,
    const float* __restrict__ a_dst, const float* __restrict__ b1,
    float* __restrict__ x1, float* __restrict__ alpha1) {
  int wave = threadIdx.x >> 6, lane = threadIdx.x & 63;
  int n = blockIdx.x * 4 + wave;
  if (n >= N_NODES) return;
  int hd = lane >> 3;
  float adn = a_dst[n * 8 + hd];
  int start = rowptr[n], end = rowptr[n + 1];
  float denom = 0.f, msg = 0.f;
  for (int p = start; p < end; ++p) {
    int e = eid[p];
    int s = e < NUM_EDGES ? ei[e] : e - NUM_EDGES;
    float sc = a_src[s * 8 + hd] + adn;
    sc = sc > 0.f ? sc : 0.2f * sc;
    float ev = __expf(sc);
    denom += ev;
    msg = fmaf(ev, H[(size_t)s * 128 + 64 + lane], msg);
  }
  float invd = 1.f / (denom + 1e-16f);
  float h1v = msg * invd + b1[lane];
  float x1v = h1v + H[(size_t)n * 128 + lane];   // residual part
  x1v = x1v > 0.f ? x1v : __expf(x1v) - 1.f;     // elu
  x1[(size_t)n * 64 + lane] = x1v;

  // alpha writes: 8 edges per iteration, lane -> (edge offset lane>>3, head lane&7)
  int h8 = lane & 7;
  float invh = __shfl(invd, h8 * 8);
  float adh = a_dst[n * 8 + h8];
  for (int p = start; p < end; p += 8) {
    int idx = p + (lane >> 3);
    if (idx < end) {
      int e = eid[idx];
      int s = e < NUM_EDGES ? ei[e] : e - NUM_EDGES;
      float sc = a_src[s * 8 + h8] + adh;
      sc = sc > 0.f ? sc : 0.2f * sc;
      alpha1[(size_t)e * 8 + h8] = __expf(sc) * invh;
    }
  }
}

// ---------------- layer-2 prep: h2 = x1 @ w2 (+attn logits) -----------------
__global__ __launch_bounds__(256) void k_layer2prep(const float* __restrict__ x1,
    const float* __restrict__ w2, const float* __restrict__ att_src2,
    const float* __restrict__ att_dst2, float* __restrict__ h2p,
    float* __restrict__ a_src2, float* __restrict__ a_dst2) {
  __shared__ float w2s[64 * 30];
  for (int i = threadIdx.x; i < 64 * 30; i += 256) w2s[i] = w2[i];
  __syncthreads();
  int wave = threadIdx.x >> 6, lane = threadIdx.x & 63;
  int n = blockIdx.x * 4 + wave;
  if (n >= N_NODES) return;
  float acc = 0.f;
  const float* xr = &x1[(size_t)n * 64];
  if (lane < 30) {
#pragma unroll 8
    for (int k = 0; k < 64; ++k) acc = fmaf(xr[k], w2s[k * 30 + lane], acc);
  }
  float as = (lane < 30) ? acc * att_src2[lane] : 0.f;
  float ad = (lane < 30) ? acc * att_dst2[lane] : 0.f;
  for (int off = 1; off < 64; off <<= 1) {
    as += __shfl_xor(as, off);
    ad += __shfl_xor(ad, off);
  }
  if (lane == 0) { a_src2[n] = as; a_dst2[n] = ad; }
  if (lane < 32) h2p[(size_t)n * 32 + lane] = (lane < 30) ? acc : 0.f;
}

// ---------------- layer-2 aggregation + elu + log_softmax + alpha2 ----------
__global__ __launch_bounds__(256) void k_layer2(const int* __restrict__ ei,
    const int* __restrict__ rowptr, const int* __restrict__ eid,
    const float* __restrict__ h2p, const float* __restrict__ a_src2,
    const float* __restrict__ a_dst2, const float* __restrict__ b2,
    float* __restrict__ out0, float* __restrict__ alpha2) {
  int wave = threadIdx.x >> 6, lane = threadIdx.x & 63;
  int n = blockIdx.x * 4 + wave;
  if (n >= N_NODES) return;
  float adn = a_dst2[n];
  int start = rowptr[n], end = rowptr[n + 1];
  bool act = lane < 30;
  float denom = 0.f, msg = 0.f;
  for (int p = start; p < end; ++p) {
    int e = eid[p];
    int s = e < NUM_EDGES ? ei[e] : e - NUM_EDGES;
    float sc = a_src2[s] + adn;
    sc = sc > 0.f ? sc : 0.2f * sc;
    float ev = __expf(sc);
    denom += ev;
    if (act) msg = fmaf(ev, h2p[(size_t)s * 32 + lane], msg);
  }
  float invd = 1.f / (denom + 1e-16f);
  float o = act ? msg * invd + b2[lane] : 0.f;
  float x2 = o > 0.f ? o : __expf(o) - 1.f;      // elu
  float mv = act ? x2 : -1e30f;
  for (int off = 1; off < 64; off <<= 1) mv = fmaxf(mv, __shfl_xor(mv, off));
  float ex = act ? __expf(x2 - mv) : 0.f;
  for (int off = 1; off < 64; off <<= 1) ex += __shfl_xor(ex, off);
  if (act) out0[(size_t)n * 30 + lane] = x2 - mv - __logf(ex);
  // alpha2: one edge per lane
  for (int p = start; p < end; p += 64) {
    int idx = p + lane;
    if (idx < end) {
      int e = eid[idx];
      int s = e < NUM_EDGES ? ei[e] : e - NUM_EDGES;
      float sc = a_src2[s] + adn;
      sc = sc > 0.f ? sc : 0.2f * sc;
      alpha2[e] = __expf(sc) * invd;
    }
  }
}

extern "C" void kernel_launch(void* const* d_in, const int* in_sizes, int n_in,
                              void* d_out, int out_size, void* d_ws, size_t ws_size,
                              hipStream_t stream) {
  const float* x        = (const float*)d_in[0];
  const int*   ei       = (const int*)d_in[1];
  const float* w_res    = (const float*)d_in[2];
  const float* b_res    = (const float*)d_in[3];
  const float* w1       = (const float*)d_in[4];
  const float* att_src1 = (const float*)d_in[5];
  const float* att_dst1 = (const float*)d_in[6];
  const float* b1       = (const float*)d_in[7];
  const float* w2       = (const float*)d_in[8];
  const float* att_src2 = (const float*)d_in[9];
  const float* att_dst2 = (const float*)d_in[10];
  const float* b2       = (const float*)d_in[11];

  float* ws = (float*)d_ws;
  float* H       = ws;                                  // [N][128]
  float* a_src1  = H + (size_t)N_NODES * 128;           // [N][8]
  float* a_dst1  = a_src1 + (size_t)N_NODES * 8;        // [N][8]
  float* x1      = a_dst1 + (size_t)N_NODES * 8;        // [N][64]
  float* h2p     = x1 + (size_t)N_NODES * 64;           // [N][32]
  float* a_src2  = h2p + (size_t)N_NODES * 32;          // [N]
  float* a_dst2  = a_src2 + N_NODES;                    // [N]
  int*   deg     = (int*)(a_dst2 + N_NODES);            // [N]
  int*   rowptr  = deg + N_NODES;                       // [N+1] (pad)
  int*   cursor  = rowptr + N_NODES + 16;               // [N]
  int*   eid     = cursor + N_NODES;                    // [E_TOTAL]

  float* out0   = (float*)d_out;                        // [N][30]
  float* alpha1 = out0 + (size_t)N_NODES * 30;          // [E_TOTAL][8]
  float* alpha2 = alpha1 + (size_t)E_TOTAL * 8;         // [E_TOTAL]

  hipMemsetAsync(deg, 0, N_NODES * sizeof(int), stream);
  hipMemsetAsync(cursor, 0, N_NODES * sizeof(int), stream);

  k_gemm<<<(N_NODES + 63) / 64, 256, 0, stream>>>(x, w_res, w1, b_res, H);
  k_attn1<<<(N_NODES * HEADS + 255) / 256, 256, 0, stream>>>(H, att_src1, att_dst1,
                                                             a_src1, a_dst1);
  k_degree<<<(E_TOTAL + 255) / 256, 256, 0, stream>>>(ei, deg);
  k_scan<<<1, 1024, 0, stream>>>(deg, rowptr);
  k_fill<<<(E_TOTAL + 255) / 256, 256, 0, stream>>>(ei, rowptr, cursor, eid);
  k_layer1<<<(N_NODES + 3) / 4, 256, 0, stream>>>(ei, rowptr, eid, H, a_src1, a_dst1,
                                                  b1, x1, alpha1);
  k_layer2prep<<<(N_NODES + 3) / 4, 256, 0, stream>>>(x1, w2, att_src2, att_dst2,
                                                      h2p, a_src2, a_dst2);
  k_layer2<<<(N_NODES + 3) / 4, 256, 0, stream>>>(ei, rowptr, eid, h2p, a_src2,
                                                  a_dst2, b2, out0, alpha2);
}

// Round 2
// 1170.633 us; speedup vs baseline: 1.1253x; 1.1253x over previous
//
#include <hip/hip_runtime.h>
#include <hip/hip_bf16.h>

#define N_NODES 50000
#define NUM_FEAT 2000
#define HEADS 8
#define HID 8
#define NUM_CLASSES 30
#define NUM_EDGES 1600000
#define E_TOTAL (NUM_EDGES + N_NODES)
#define KSTEPS 63   // ceil(2000/32)

typedef __attribute__((ext_vector_type(8))) short short8;
typedef __attribute__((ext_vector_type(4))) float f32x4;

__device__ __forceinline__ ushort f2bf(float f) {
  __hip_bfloat16 b = __float2bfloat16(f);
  return *reinterpret_cast<ushort*>(&b);
}

// ---- pack weights into per-K-step LDS fragment image: [t][kg][col][j] -------
// col 0..63 -> w_res, 64..127 -> w1 ; k = t*32 + kg*8 + j ; zero-pad k>=2000.
__global__ void k_prepB(const float* __restrict__ Wres, const float* __restrict__ W1,
                        ushort* __restrict__ Bp) {
  int i = blockIdx.x * 256 + threadIdx.x;          // i = (t*4+kg)*128 + col
  if (i >= KSTEPS * 4 * 128) return;
  int col = i & 127;
  int kbase = (i >> 7) * 8;
  const float* W = (col < 64) ? Wres : W1;
  int c = col & 63;
  union { short8 v; ushort u[8]; } p;
#pragma unroll
  for (int j = 0; j < 8; ++j) {
    int k = kbase + j;
    p.u[j] = f2bf(k < NUM_FEAT ? W[(size_t)k * 64 + c] : 0.f);
  }
  *(short8*)&Bp[(size_t)i * 8] = p.v;
}

// ---- MFMA GEMM: H[n][0:64] = x@w_res + b_res ; H[n][64:128] = x@w1 ----------
// BM=128, BN=128(full), BK=32; 4 waves (2x2), each 64x64 via 4x4 16x16x32 MFMAs.
__global__ __launch_bounds__(256) void k_gemm_mfma(const float* __restrict__ X,
    const ushort* __restrict__ Bp, const float* __restrict__ brs,
    float* __restrict__ H) {
  __shared__ ushort lds[2][2][4096];               // [buf][A=0/B=1][kg*128+row][8]
  const int tid = threadIdx.x;
  const int lane = tid & 63, wid = tid >> 6;
  const int wr = wid >> 1, wc = wid & 1;
  const int m0 = blockIdx.x * 128;

  // A staging: thread handles rows {rowA, rowA+64} x k-group kgA (8 floats each)
  const int kgA = tid & 3;
  const int rowA = tid >> 2;                       // 0..63
  int rg0 = m0 + rowA;      rg0 = rg0 < N_NODES ? rg0 : N_NODES - 1;
  int rg1 = m0 + rowA + 64; rg1 = rg1 < N_NODES ? rg1 : N_NODES - 1;
  const float* ax0 = X + (size_t)rg0 * NUM_FEAT + kgA * 8;
  const float* ax1 = X + (size_t)rg1 * NUM_FEAT + kgA * 8;

  f32x4 acc[4][4] = {};
  float4 ra[4];
  short8 rb[2];

  auto loadA = [&](int t) {
    int k0 = t * 32 + kgA * 8;
    bool v0 = k0 < NUM_FEAT, v1 = k0 + 4 < NUM_FEAT;
    float4 z = make_float4(0.f, 0.f, 0.f, 0.f);
    ra[0] = v0 ? *(const float4*)(ax0 + t * 32) : z;
    ra[1] = v1 ? *(const float4*)(ax0 + t * 32 + 4) : z;
    ra[2] = v0 ? *(const float4*)(ax1 + t * 32) : z;
    ra[3] = v1 ? *(const float4*)(ax1 + t * 32 + 4) : z;
  };
  auto loadB = [&](int t) {
    const short8* src = (const short8*)(Bp + (size_t)t * 4096);
    rb[0] = src[tid];
    rb[1] = src[tid + 256];
  };
  auto writeA = [&](int buf) {
    union { short8 v; ushort u[8]; } p;
    p.u[0] = f2bf(ra[0].x); p.u[1] = f2bf(ra[0].y); p.u[2] = f2bf(ra[0].z); p.u[3] = f2bf(ra[0].w);
    p.u[4] = f2bf(ra[1].x); p.u[5] = f2bf(ra[1].y); p.u[6] = f2bf(ra[1].z); p.u[7] = f2bf(ra[1].w);
    *(short8*)&lds[buf][0][(size_t)(kgA * 128 + rowA) * 8] = p.v;
    p.u[0] = f2bf(ra[2].x); p.u[1] = f2bf(ra[2].y); p.u[2] = f2bf(ra[2].z); p.u[3] = f2bf(ra[2].w);
    p.u[4] = f2bf(ra[3].x); p.u[5] = f2bf(ra[3].y); p.u[6] = f2bf(ra[3].z); p.u[7] = f2bf(ra[3].w);
    *(short8*)&lds[buf][0][(size_t)(kgA * 128 + rowA + 64) * 8] = p.v;
  };
  auto writeB = [&](int buf) {
    *(short8*)&lds[buf][1][(size_t)tid * 8] = rb[0];
    *(short8*)&lds[buf][1][(size_t)(tid + 256) * 8] = rb[1];
  };

  loadA(0); loadB(0);
  writeA(0); writeB(0);
  __syncthreads();

  const int lg = lane >> 4, lr = lane & 15;
  for (int t = 0; t < KSTEPS; ++t) {
    int cur = t & 1, nxt = cur ^ 1;
    if (t + 1 < KSTEPS) { loadA(t + 1); loadB(t + 1); }
    const ushort* A = &lds[cur][0][0];
    const ushort* B = &lds[cur][1][0];
    short8 fa[4], fb[4];
#pragma unroll
    for (int m = 0; m < 4; ++m)
      fa[m] = *(const short8*)&A[(size_t)(lg * 128 + wr * 64 + m * 16 + lr) * 8];
#pragma unroll
    for (int n = 0; n < 4; ++n)
      fb[n] = *(const short8*)&B[(size_t)(lg * 128 + wc * 64 + n * 16 + lr) * 8];
#pragma unroll
    for (int m = 0; m < 4; ++m)
#pragma unroll
      for (int n = 0; n < 4; ++n)
        acc[m][n] = __builtin_amdgcn_mfma_f32_16x16x32_bf16(fa[m], fb[n], acc[m][n], 0, 0, 0);
    if (t + 1 < KSTEPS) { writeA(nxt); writeB(nxt); }
    __syncthreads();
  }

  // epilogue: C/D map col=lane&15, row=(lane>>4)*4+i  [m89-verified]
#pragma unroll
  for (int m = 0; m < 4; ++m) {
#pragma unroll
    for (int n = 0; n < 4; ++n) {
      int col = wc * 64 + n * 16 + lr;
      float badd = (col < 64) ? brs[col] : 0.f;
#pragma unroll
      for (int i = 0; i < 4; ++i) {
        int row = m0 + wr * 64 + m * 16 + lg * 4 + i;
        if (row < N_NODES) H[(size_t)row * 128 + col] = acc[m][n][i] + badd;
      }
    }
  }
}

// ---------------- per-node attention logits for layer 1 ---------------------
__global__ void k_attn1(const float* __restrict__ H, const float* __restrict__ att_src,
                        const float* __restrict__ att_dst, float* __restrict__ a_src,
                        float* __restrict__ a_dst) {
  int i = blockIdx.x * blockDim.x + threadIdx.x;  // i = n*8 + h
  if (i >= N_NODES * HEADS) return;
  int h = i & 7;
  const float* hp = &H[(size_t)(i >> 3) * 128 + 64 + h * 8];
  float s = 0.f, d = 0.f;
#pragma unroll
  for (int c = 0; c < 8; ++c) {
    float v = hp[c];
    s = fmaf(v, att_src[h * 8 + c], s);
    d = fmaf(v, att_dst[h * 8 + c], d);
  }
  a_src[i] = s; a_dst[i] = d;
}

// ---------------- CSR build (by dst) ----------------------------------------
__global__ void k_degree(const int* __restrict__ ei, int* __restrict__ deg) {
  int e = blockIdx.x * blockDim.x + threadIdx.x;
  if (e >= E_TOTAL) return;
  int d = e < NUM_EDGES ? ei[NUM_EDGES + e] : e - NUM_EDGES;
  atomicAdd(&deg[d], 1);
}

__global__ __launch_bounds__(1024) void k_scan(const int* __restrict__ deg,
                                               int* __restrict__ rowptr) {
  __shared__ int smem[1024];
  int t = threadIdx.x;
  int carry = 0;
  if (t == 0) rowptr[0] = 0;
  for (int base = 0; base < N_NODES; base += 1024) {
    int i = base + t;
    int v = (i < N_NODES) ? deg[i] : 0;
    smem[t] = v; __syncthreads();
    for (int off = 1; off < 1024; off <<= 1) {
      int add = (t >= off) ? smem[t - off] : 0;
      __syncthreads();
      smem[t] += add;
      __syncthreads();
    }
    int inc = smem[t];
    int tot = smem[1023];
    if (i < N_NODES) rowptr[i + 1] = carry + inc;
    carry += tot;
    __syncthreads();
  }
}

__global__ void k_fill(const int* __restrict__ ei, const int* __restrict__ rowptr,
                       int* __restrict__ cursor, int* __restrict__ eid) {
  int e = blockIdx.x * blockDim.x + threadIdx.x;
  if (e >= E_TOTAL) return;
  int d = e < NUM_EDGES ? ei[NUM_EDGES + e] : e - NUM_EDGES;
  int pos = atomicAdd(&cursor[d], 1);
  eid[rowptr[d] + pos] = e;
}

// ---------------- layer-1 aggregation: one wave per node, lane = (head*8+c) --
__global__ __launch_bounds__(256) void k_layer1(const int* __restrict__ ei,
    const int* __restrict__ rowptr, const int* __restrict__ eid,
    const float* __restrict__ H, const float* __restrict__ a_src,
    const float* __restrict__ a_dst, const float* __restrict__ b1,
    float* __restrict__ x1, float* __restrict__ alpha1) {
  int wave = threadIdx.x >> 6, lane = threadIdx.x & 63;
  int n = blockIdx.x * 4 + wave;
  if (n >= N_NODES) return;
  int hd = lane >> 3;
  float adn = a_dst[n * 8 + hd];
  int start = rowptr[n], end = rowptr[n + 1];
  float denom = 0.f, msg = 0.f;
  for (int p = start; p < end; ++p) {
    int e = eid[p];
    int s = e < NUM_EDGES ? ei[e] : e - NUM_EDGES;
    float sc = a_src[s * 8 + hd] + adn;
    sc = sc > 0.f ? sc : 0.2f * sc;
    float ev = __expf(sc);
    denom += ev;
    msg = fmaf(ev, H[(size_t)s * 128 + 64 + lane], msg);
  }
  float invd = 1.f / (denom + 1e-16f);
  float h1v = msg * invd + b1[lane];
  float x1v = h1v + H[(size_t)n * 128 + lane];   // residual part
  x1v = x1v > 0.f ? x1v : __expf(x1v) - 1.f;     // elu
  x1[(size_t)n * 64 + lane] = x1v;

  // alpha writes: 8 edges per iteration, lane -> (edge offset lane>>3, head lane&7)
  int h8 = lane & 7;
  float invh = __shfl(invd, h8 * 8);
  float adh = a_dst[n * 8 + h8];
  for (int p = start; p < end; p += 8) {
    int idx = p + (lane >> 3);
    if (idx < end) {
      int e = eid[idx];
      int s = e < NUM_EDGES ? ei[e] : e - NUM_EDGES;
      float sc = a_src[s * 8 + h8] + adh;
      sc = sc > 0.f ? sc : 0.2f * sc;
      alpha1[(size_t)e * 8 + h8] = __expf(sc) * invh;
    }
  }
}

// ---------------- layer-2 prep: h2 = x1 @ w2 (+attn logits) -----------------
__global__ __launch_bounds__(256) void k_layer2prep(const float* __restrict__ x1,
    const float* __restrict__ w2, const float* __restrict__ att_src2,
    const float* __restrict__ att_dst2, float* __restrict__ h2p,
    float* __restrict__ a_src2, float* __restrict__ a_dst2) {
  __shared__ float w2s[64 * 30];
  for (int i = threadIdx.x; i < 64 * 30; i += 256) w2s[i] = w2[i];
  __syncthreads();
  int wave = threadIdx.x >> 6, lane = threadIdx.x & 63;
  int n = blockIdx.x * 4 + wave;
  if (n >= N_NODES) return;
  float acc = 0.f;
  const float* xr = &x1[(size_t)n * 64];
  if (lane < 30) {
#pragma unroll 8
    for (int k = 0; k < 64; ++k) acc = fmaf(xr[k], w2s[k * 30 + lane], acc);
  }
  float as = (lane < 30) ? acc * att_src2[lane] : 0.f;
  float ad = (lane < 30) ? acc * att_dst2[lane] : 0.f;
  for (int off = 1; off < 64; off <<= 1) {
    as += __shfl_xor(as, off);
    ad += __shfl_xor(ad, off);
  }
  if (lane == 0) { a_src2[n] = as; a_dst2[n] = ad; }
  if (lane < 32) h2p[(size_t)n * 32 + lane] = (lane < 30) ? acc : 0.f;
}

// ---------------- layer-2 aggregation + elu + log_softmax + alpha2 ----------
__global__ __launch_bounds__(256) void k_layer2(const int* __restrict__ ei,
    const int* __restrict__ rowptr, const int* __restrict__ eid,
    const float* __restrict__ h2p, const float* __restrict__ a_src2,
    const float* __restrict__ a_dst2, const float* __restrict__ b2,
    float* __restrict__ out0, float* __restrict__ alpha2) {
  int wave = threadIdx.x >> 6, lane = threadIdx.x & 63;
  int n = blockIdx.x * 4 + wave;
  if (n >= N_NODES) return;
  float adn = a_dst2[n];
  int start = rowptr[n], end = rowptr[n + 1];
  bool act = lane < 30;
  float denom = 0.f, msg = 0.f;
  for (int p = start; p < end; ++p) {
    int e = eid[p];
    int s = e < NUM_EDGES ? ei[e] : e - NUM_EDGES;
    float sc = a_src2[s] + adn;
    sc = sc > 0.f ? sc : 0.2f * sc;
    float ev = __expf(sc);
    denom += ev;
    if (act) msg = fmaf(ev, h2p[(size_t)s * 32 + lane], msg);
  }
  float invd = 1.f / (denom + 1e-16f);
  float o = act ? msg * invd + b2[lane] : 0.f;
  float x2 = o > 0.f ? o : __expf(o) - 1.f;      // elu
  float mv = act ? x2 : -1e30f;
  for (int off = 1; off < 64; off <<= 1) mv = fmaxf(mv, __shfl_xor(mv, off));
  float ex = act ? __expf(x2 - mv) : 0.f;
  for (int off = 1; off < 64; off <<= 1) ex += __shfl_xor(ex, off);
  if (act) out0[(size_t)n * 30 + lane] = x2 - mv - __logf(ex);
  // alpha2: one edge per lane
  for (int p = start; p < end; p += 64) {
    int idx = p + lane;
    if (idx < end) {
      int e = eid[idx];
      int s = e < NUM_EDGES ? ei[e] : e - NUM_EDGES;
      float sc = a_src2[s] + adn;
      sc = sc > 0.f ? sc : 0.2f * sc;
      alpha2[e] = __expf(sc) * invd;
    }
  }
}

extern "C" void kernel_launch(void* const* d_in, const int* in_sizes, int n_in,
                              void* d_out, int out_size, void* d_ws, size_t ws_size,
                              hipStream_t stream) {
  const float* x        = (const float*)d_in[0];
  const int*   ei       = (const int*)d_in[1];
  const float* w_res    = (const float*)d_in[2];
  const float* b_res    = (const float*)d_in[3];
  const float* w1       = (const float*)d_in[4];
  const float* att_src1 = (const float*)d_in[5];
  const float* att_dst1 = (const float*)d_in[6];
  const float* b1       = (const float*)d_in[7];
  const float* w2       = (const float*)d_in[8];
  const float* att_src2 = (const float*)d_in[9];
  const float* att_dst2 = (const float*)d_in[10];
  const float* b2       = (const float*)d_in[11];

  float* ws = (float*)d_ws;
  float* H       = ws;                                  // [N][128]
  float* a_src1  = H + (size_t)N_NODES * 128;           // [N][8]
  float* a_dst1  = a_src1 + (size_t)N_NODES * 8;        // [N][8]
  float* x1      = a_dst1 + (size_t)N_NODES * 8;        // [N][64]
  float* h2p     = x1 + (size_t)N_NODES * 64;           // [N][32]
  float* a_src2  = h2p + (size_t)N_NODES * 32;          // [N]
  float* a_dst2  = a_src2 + N_NODES;                    // [N]
  int*   deg     = (int*)(a_dst2 + N_NODES);            // [N]
  int*   rowptr  = deg + N_NODES;                       // [N+1] (pad)
  int*   cursor  = rowptr + N_NODES + 16;               // [N]
  int*   eid     = cursor + N_NODES;                    // [E_TOTAL]
  // Bp aliases x1 (dead before k_layer1 writes x1): 63*4096 bf16 = 516 KB << 12.8 MB
  ushort* Bp     = (ushort*)x1;

  float* out0   = (float*)d_out;                        // [N][30]
  float* alpha1 = out0 + (size_t)N_NODES * 30;          // [E_TOTAL][8]
  float* alpha2 = alpha1 + (size_t)E_TOTAL * 8;         // [E_TOTAL]

  hipMemsetAsync(deg, 0, N_NODES * sizeof(int), stream);
  hipMemsetAsync(cursor, 0, N_NODES * sizeof(int), stream);

  k_prepB<<<(KSTEPS * 4 * 128 + 255) / 256, 256, 0, stream>>>(w_res, w1, Bp);
  k_gemm_mfma<<<(N_NODES + 127) / 128, 256, 0, stream>>>(x, Bp, b_res, H);
  k_attn1<<<(N_NODES * HEADS + 255) / 256, 256, 0, stream>>>(H, att_src1, att_dst1,
                                                             a_src1, a_dst1);
  k_degree<<<(E_TOTAL + 255) / 256, 256, 0, stream>>>(ei, deg);
  k_scan<<<1, 1024, 0, stream>>>(deg, rowptr);
  k_fill<<<(E_TOTAL + 255) / 256, 256, 0, stream>>>(ei, rowptr, cursor, eid);
  k_layer1<<<(N_NODES + 3) / 4, 256, 0, stream>>>(ei, rowptr, eid, H, a_src1, a_dst1,
                                                  b1, x1, alpha1);
  k_layer2prep<<<(N_NODES + 3) / 4, 256, 0, stream>>>(x1, w2, att_src2, att_dst2,
                                                      h2p, a_src2, a_dst2);
  k_layer2<<<(N_NODES + 3) / 4, 256, 0, stream>>>(ei, rowptr, eid, h2p, a_src2,
                                                  a_dst2, b2, out0, alpha2);
}

// Round 3
// 805.312 us; speedup vs baseline: 1.6358x; 1.4536x over previous
//
#include <hip/hip_runtime.h>
#include <hip/hip_bf16.h>

#define N_NODES 50000
#define NUM_FEAT 2000
#define HEADS 8
#define HID 8
#define NUM_CLASSES 30
#define NUM_EDGES 1600000
#define E_TOTAL (NUM_EDGES + N_NODES)
#define KSTEPS 63   // ceil(2000/32)

typedef __attribute__((ext_vector_type(8))) short short8;
typedef __attribute__((ext_vector_type(4))) float f32x4;

typedef __attribute__((address_space(1))) const unsigned int gu32;
typedef __attribute__((address_space(3))) unsigned int lu32;

__device__ __forceinline__ void gload_lds16(const void* g, void* l) {
  __builtin_amdgcn_global_load_lds((gu32*)g, (lu32*)l, 16, 0, 0);
}

__device__ __forceinline__ ushort f2bf(float f) {
  __hip_bfloat16 b = __float2bfloat16(f);
  return *reinterpret_cast<ushort*>(&b);
}

__device__ __forceinline__ short8 cvt8(float4 a, float4 b) {
  union { short8 v; ushort u[8]; } p;
  p.u[0] = f2bf(a.x); p.u[1] = f2bf(a.y); p.u[2] = f2bf(a.z); p.u[3] = f2bf(a.w);
  p.u[4] = f2bf(b.x); p.u[5] = f2bf(b.y); p.u[6] = f2bf(b.z); p.u[7] = f2bf(b.w);
  return p.v;
}

// ---- pack weights into per-K-step LDS fragment image: [t][kg][col][j] -------
// col 0..63 -> w_res, 64..127 -> w1 ; k = t*32 + kg*8 + j ; zero-pad k>=2000.
__global__ void k_prepB(const float* __restrict__ Wres, const float* __restrict__ W1,
                        ushort* __restrict__ Bp) {
  int i = blockIdx.x * 256 + threadIdx.x;          // i = (t*4+kg)*128 + col
  if (i >= KSTEPS * 4 * 128) return;
  int col = i & 127;
  int kbase = (i >> 7) * 8;
  const float* W = (col < 64) ? Wres : W1;
  int c = col & 63;
  union { short8 v; ushort u[8]; } p;
#pragma unroll
  for (int j = 0; j < 8; ++j) {
    int k = kbase + j;
    p.u[j] = f2bf(k < NUM_FEAT ? W[(size_t)k * 64 + c] : 0.f);
  }
  *(short8*)&Bp[(size_t)i * 8] = p.v;
}

// ---- MFMA GEMM: H[n][0:64] = x@w_res + b_res ; H[n][64:128] = x@w1 ----------
// BM=64, 4 waves, each wave: 16 rows x 128 cols (1x8 frags). A: global->reg,
// convert to bf16 in-register (double-buffered). B: global_load_lds dbuf.
__global__ __launch_bounds__(256) void k_gemm_mfma(const float* __restrict__ X,
    const ushort* __restrict__ Bp, const float* __restrict__ brs,
    float* __restrict__ H) {
  __shared__ ushort ldsB[2][4096];                 // [buf][kg*128+col][8]
  const int tid = threadIdx.x;
  const int lane = tid & 63, wid = tid >> 6;
  const int lg = lane >> 4, lr = lane & 15;
  const int m0 = blockIdx.x * 64;

  int rowg = m0 + wid * 16 + lr;
  rowg = rowg < N_NODES ? rowg : N_NODES - 1;
  const float* axp = X + (size_t)rowg * NUM_FEAT + lg * 8;

  f32x4 acc[8] = {};
  float4 a0, a1, na0, na1;
  const float4 fz = make_float4(0.f, 0.f, 0.f, 0.f);

  auto loadA = [&](int t, float4& r0, float4& r1) {
    int k0 = t * 32 + lg * 8;
    if (k0 < NUM_FEAT) {
      r0 = *(const float4*)(axp + t * 32);
      r1 = *(const float4*)(axp + t * 32 + 4);
    } else { r0 = fz; r1 = fz; }
  };
  auto stageB = [&](int t, int buf) {
    const ushort* g0 = Bp + (size_t)t * 4096 + (size_t)(wid * 64 + lane) * 8;
    gload_lds16(g0, &ldsB[buf][(size_t)(wid * 64) * 8]);
    gload_lds16(g0 + 2048, &ldsB[buf][(size_t)(256 + wid * 64) * 8]);
  };

  stageB(0, 0);
  loadA(0, a0, a1);
  __syncthreads();

  for (int t = 0; t < KSTEPS - 1; ++t) {
    const int cur = t & 1, nxt = cur ^ 1;
    stageB(t + 1, nxt);
    short8 fb[8];
#pragma unroll
    for (int n = 0; n < 8; ++n)
      fb[n] = *(const short8*)&ldsB[cur][(size_t)(lg * 128 + n * 16 + lr) * 8];
    loadA(t + 1, na0, na1);
    short8 fa = cvt8(a0, a1);
#pragma unroll
    for (int n = 0; n < 8; ++n)
      acc[n] = __builtin_amdgcn_mfma_f32_16x16x32_bf16(fa, fb[n], acc[n], 0, 0, 0);
    a0 = na0; a1 = na1;
    __syncthreads();
  }
  {
    const int cur = (KSTEPS - 1) & 1;
    short8 fb[8];
#pragma unroll
    for (int n = 0; n < 8; ++n)
      fb[n] = *(const short8*)&ldsB[cur][(size_t)(lg * 128 + n * 16 + lr) * 8];
    short8 fa = cvt8(a0, a1);
#pragma unroll
    for (int n = 0; n < 8; ++n)
      acc[n] = __builtin_amdgcn_mfma_f32_16x16x32_bf16(fa, fb[n], acc[n], 0, 0, 0);
  }

  // epilogue: C/D map col=lane&15, row=(lane>>4)*4+i  [m89-verified]
#pragma unroll
  for (int n = 0; n < 8; ++n) {
    int col = n * 16 + lr;
    float badd = (col < 64) ? brs[col] : 0.f;
#pragma unroll
    for (int i = 0; i < 4; ++i) {
      int row = m0 + wid * 16 + lg * 4 + i;
      if (row < N_NODES) H[(size_t)row * 128 + col] = acc[n][i] + badd;
    }
  }
}

// ---------------- per-node attention logits for layer 1 ---------------------
__global__ void k_attn1(const float* __restrict__ H, const float* __restrict__ att_src,
                        const float* __restrict__ att_dst, float* __restrict__ a_src,
                        float* __restrict__ a_dst) {
  int i = blockIdx.x * blockDim.x + threadIdx.x;  // i = n*8 + h
  if (i >= N_NODES * HEADS) return;
  int h = i & 7;
  const float* hp = &H[(size_t)(i >> 3) * 128 + 64 + h * 8];
  float s = 0.f, d = 0.f;
#pragma unroll
  for (int c = 0; c < 8; ++c) {
    float v = hp[c];
    s = fmaf(v, att_src[h * 8 + c], s);
    d = fmaf(v, att_dst[h * 8 + c], d);
  }
  a_src[i] = s; a_dst[i] = d;
}

// ---------------- CSR build (by dst) ----------------------------------------
__global__ void k_degree(const int* __restrict__ ei, int* __restrict__ deg) {
  int e = blockIdx.x * blockDim.x + threadIdx.x;
  if (e >= E_TOTAL) return;
  int d = e < NUM_EDGES ? ei[NUM_EDGES + e] : e - NUM_EDGES;
  atomicAdd(&deg[d], 1);
}

__global__ __launch_bounds__(1024) void k_scan(const int* __restrict__ deg,
                                               int* __restrict__ rowptr) {
  __shared__ int smem[1024];
  int t = threadIdx.x;
  int carry = 0;
  if (t == 0) rowptr[0] = 0;
  for (int base = 0; base < N_NODES; base += 1024) {
    int i = base + t;
    int v = (i < N_NODES) ? deg[i] : 0;
    smem[t] = v; __syncthreads();
    for (int off = 1; off < 1024; off <<= 1) {
      int add = (t >= off) ? smem[t - off] : 0;
      __syncthreads();
      smem[t] += add;
      __syncthreads();
    }
    int inc = smem[t];
    int tot = smem[1023];
    if (i < N_NODES) rowptr[i + 1] = carry + inc;
    carry += tot;
    __syncthreads();
  }
}

__global__ void k_fill(const int* __restrict__ ei, const int* __restrict__ rowptr,
                       int* __restrict__ cursor, int* __restrict__ eid) {
  int e = blockIdx.x * blockDim.x + threadIdx.x;
  if (e >= E_TOTAL) return;
  int d = e < NUM_EDGES ? ei[NUM_EDGES + e] : e - NUM_EDGES;
  int pos = atomicAdd(&cursor[d], 1);
  eid[rowptr[d] + pos] = e;
}

// ---------------- layer-1 aggregation: one wave per node, lane = (head*8+c) --
__global__ __launch_bounds__(256) void k_layer1(const int* __restrict__ ei,
    const int* __restrict__ rowptr, const int* __restrict__ eid,
    const float* __restrict__ H, const float* __restrict__ a_src,
    const float* __restrict__ a_dst, const float* __restrict__ b1,
    float* __restrict__ x1, float* __restrict__ alpha1) {
  int wave = threadIdx.x >> 6, lane = threadIdx.x & 63;
  int n = blockIdx.x * 4 + wave;
  if (n >= N_NODES) return;
  int hd = lane >> 3;
  float adn = a_dst[n * 8 + hd];
  int start = rowptr[n], end = rowptr[n + 1];
  float denom = 0.f, msg = 0.f;
  // 4 edges in flight per iteration: 4 independent eid->ei->gather chains
  for (int p = start; p < end; p += 4) {
    int s4[4];
#pragma unroll
    for (int i = 0; i < 4; ++i) {
      int idx = p + i; idx = idx < end ? idx : end - 1;
      int e = eid[idx];
      s4[i] = e < NUM_EDGES ? ei[e] : e - NUM_EDGES;
    }
    float av[4], hv[4];
#pragma unroll
    for (int i = 0; i < 4; ++i) {
      av[i] = a_src[s4[i] * 8 + hd];
      hv[i] = H[(size_t)s4[i] * 128 + 64 + lane];
    }
#pragma unroll
    for (int i = 0; i < 4; ++i) {
      if (p + i < end) {
        float sc = av[i] + adn;
        sc = sc > 0.f ? sc : 0.2f * sc;
        float ev = __expf(sc);
        denom += ev;
        msg = fmaf(ev, hv[i], msg);
      }
    }
  }
  float invd = 1.f / (denom + 1e-16f);
  float h1v = msg * invd + b1[lane];
  float x1v = h1v + H[(size_t)n * 128 + lane];   // residual part
  x1v = x1v > 0.f ? x1v : __expf(x1v) - 1.f;     // elu
  x1[(size_t)n * 64 + lane] = x1v;

  // alpha writes: 8 edges per iteration, lane -> (edge offset lane>>3, head lane&7)
  int h8 = lane & 7;
  float invh = __shfl(invd, h8 * 8);
  float adh = a_dst[n * 8 + h8];
  for (int p = start; p < end; p += 8) {
    int idx = p + (lane >> 3);
    if (idx < end) {
      int e = eid[idx];
      int s = e < NUM_EDGES ? ei[e] : e - NUM_EDGES;
      float sc = a_src[s * 8 + h8] + adh;
      sc = sc > 0.f ? sc : 0.2f * sc;
      alpha1[(size_t)e * 8 + h8] = __expf(sc) * invh;
    }
  }
}

// ---------------- layer-2 prep: h2 = x1 @ w2 (+attn logits) -----------------
__global__ __launch_bounds__(256) void k_layer2prep(const float* __restrict__ x1,
    const float* __restrict__ w2, const float* __restrict__ att_src2,
    const float* __restrict__ att_dst2, float* __restrict__ h2p,
    float* __restrict__ a_src2, float* __restrict__ a_dst2) {
  __shared__ float w2s[64 * 30];
  for (int i = threadIdx.x; i < 64 * 30; i += 256) w2s[i] = w2[i];
  __syncthreads();
  int wave = threadIdx.x >> 6, lane = threadIdx.x & 63;
  int n = blockIdx.x * 4 + wave;
  if (n >= N_NODES) return;
  float acc = 0.f;
  const float* xr = &x1[(size_t)n * 64];
  if (lane < 30) {
#pragma unroll 8
    for (int k = 0; k < 64; ++k) acc = fmaf(xr[k], w2s[k * 30 + lane], acc);
  }
  float as = (lane < 30) ? acc * att_src2[lane] : 0.f;
  float ad = (lane < 30) ? acc * att_dst2[lane] : 0.f;
  for (int off = 1; off < 64; off <<= 1) {
    as += __shfl_xor(as, off);
    ad += __shfl_xor(ad, off);
  }
  if (lane == 0) { a_src2[n] = as; a_dst2[n] = ad; }
  if (lane < 32) h2p[(size_t)n * 32 + lane] = (lane < 30) ? acc : 0.f;
}

// ---------------- layer-2 aggregation + elu + log_softmax + alpha2 ----------
// Both 32-lane halves process edges (2 edges in flight); combine at the end.
__global__ __launch_bounds__(256) void k_layer2(const int* __restrict__ ei,
    const int* __restrict__ rowptr, const int* __restrict__ eid,
    const float* __restrict__ h2p, const float* __restrict__ a_src2,
    const float* __restrict__ a_dst2, const float* __restrict__ b2,
    float* __restrict__ out0, float* __restrict__ alpha2) {
  int wave = threadIdx.x >> 6, lane = threadIdx.x & 63;
  int n = blockIdx.x * 4 + wave;
  if (n >= N_NODES) return;
  float adn = a_dst2[n];
  int start = rowptr[n], end = rowptr[n + 1];
  int half = lane >> 5, cls = lane & 31;
  float denom = 0.f, msg = 0.f;
  for (int p = start; p < end; p += 2) {
    int idx = p + half;
    bool valid = idx < end;
    idx = valid ? idx : end - 1;
    int e = eid[idx];
    int s = e < NUM_EDGES ? ei[e] : e - NUM_EDGES;
    float asv = a_src2[s];
    float hvv = h2p[(size_t)s * 32 + cls];   // cls 30,31 read stored zeros
    if (valid) {
      float sc = asv + adn;
      sc = sc > 0.f ? sc : 0.2f * sc;
      float ev = __expf(sc);
      denom += ev;
      msg = fmaf(ev, hvv, msg);
    }
  }
  denom += __shfl_xor(denom, 32);
  msg   += __shfl_xor(msg, 32);
  float invd = 1.f / (denom + 1e-16f);
  bool act = lane < 30;
  float o = act ? msg * invd + b2[lane] : 0.f;
  float x2 = o > 0.f ? o : __expf(o) - 1.f;      // elu
  float mv = act ? x2 : -1e30f;
  for (int off = 1; off < 64; off <<= 1) mv = fmaxf(mv, __shfl_xor(mv, off));
  float ex = act ? __expf(x2 - mv) : 0.f;
  for (int off = 1; off < 64; off <<= 1) ex += __shfl_xor(ex, off);
  if (act) out0[(size_t)n * 30 + lane] = x2 - mv - __logf(ex);
  // alpha2: one edge per lane
  for (int p = start; p < end; p += 64) {
    int idx = p + lane;
    if (idx < end) {
      int e = eid[idx];
      int s = e < NUM_EDGES ? ei[e] : e - NUM_EDGES;
      float sc = a_src2[s] + adn;
      sc = sc > 0.f ? sc : 0.2f * sc;
      alpha2[e] = __expf(sc) * invd;
    }
  }
}

extern "C" void kernel_launch(void* const* d_in, const int* in_sizes, int n_in,
                              void* d_out, int out_size, void* d_ws, size_t ws_size,
                              hipStream_t stream) {
  const float* x        = (const float*)d_in[0];
  const int*   ei       = (const int*)d_in[1];
  const float* w_res    = (const float*)d_in[2];
  const float* b_res    = (const float*)d_in[3];
  const float* w1       = (const float*)d_in[4];
  const float* att_src1 = (const float*)d_in[5];
  const float* att_dst1 = (const float*)d_in[6];
  const float* b1       = (const float*)d_in[7];
  const float* w2       = (const float*)d_in[8];
  const float* att_src2 = (const float*)d_in[9];
  const float* att_dst2 = (const float*)d_in[10];
  const float* b2       = (const float*)d_in[11];

  float* ws = (float*)d_ws;
  float* H       = ws;                                  // [N][128]
  float* a_src1  = H + (size_t)N_NODES * 128;           // [N][8]
  float* a_dst1  = a_src1 + (size_t)N_NODES * 8;        // [N][8]
  float* x1      = a_dst1 + (size_t)N_NODES * 8;        // [N][64]
  float* h2p     = x1 + (size_t)N_NODES * 64;           // [N][32]
  float* a_src2  = h2p + (size_t)N_NODES * 32;          // [N]
  float* a_dst2  = a_src2 + N_NODES;                    // [N]
  int*   deg     = (int*)(a_dst2 + N_NODES);            // [N]
  int*   rowptr  = deg + N_NODES;                       // [N+1] (pad)
  int*   cursor  = rowptr + N_NODES + 16;               // [N]
  int*   eid     = cursor + N_NODES;                    // [E_TOTAL]
  // Bp aliases x1 (dead before k_layer1 writes x1): 63*4096 bf16 = 516 KB << 12.8 MB
  ushort* Bp     = (ushort*)x1;

  float* out0   = (float*)d_out;                        // [N][30]
  float* alpha1 = out0 + (size_t)N_NODES * 30;          // [E_TOTAL][8]
  float* alpha2 = alpha1 + (size_t)E_TOTAL * 8;         // [E_TOTAL]

  hipMemsetAsync(deg, 0, N_NODES * sizeof(int), stream);
  hipMemsetAsync(cursor, 0, N_NODES * sizeof(int), stream);

  k_prepB<<<(KSTEPS * 4 * 128 + 255) / 256, 256, 0, stream>>>(w_res, w1, Bp);
  k_gemm_mfma<<<(N_NODES + 63) / 64, 256, 0, stream>>>(x, Bp, b_res, H);
  k_attn1<<<(N_NODES * HEADS + 255) / 256, 256, 0, stream>>>(H, att_src1, att_dst1,
                                                             a_src1, a_dst1);
  k_degree<<<(E_TOTAL + 255) / 256, 256, 0, stream>>>(ei, deg);
  k_scan<<<1, 1024, 0, stream>>>(deg, rowptr);
  k_fill<<<(E_TOTAL + 255) / 256, 256, 0, stream>>>(ei, rowptr, cursor, eid);
  k_layer1<<<(N_NODES + 3) / 4, 256, 0, stream>>>(ei, rowptr, eid, H, a_src1, a_dst1,
                                                  b1, x1, alpha1);
  k_layer2prep<<<(N_NODES + 3) / 4, 256, 0, stream>>>(x1, w2, att_src2, att_dst2,
                                                      h2p, a_src2, a_dst2);
  k_layer2<<<(N_NODES + 3) / 4, 256, 0, stream>>>(ei, rowptr, eid, h2p, a_src2,
                                                  a_dst2, b2, out0, alpha2);
}

// Round 4
// 686.036 us; speedup vs baseline: 1.9203x; 1.1739x over previous
//
#include <hip/hip_runtime.h>
#include <hip/hip_bf16.h>

#define N_NODES 50000
#define NUM_FEAT 2000
#define HEADS 8
#define HID 8
#define NUM_CLASSES 30
#define NUM_EDGES 1600000
#define E_TOTAL (NUM_EDGES + N_NODES)
#define KSTEPS 63   // ceil(2000/32)
#define SCAN_BLOCKS ((N_NODES + 255) / 256)   // 196

typedef __attribute__((ext_vector_type(8))) short short8;
typedef __attribute__((ext_vector_type(4))) float f32x4;

typedef __attribute__((address_space(1))) const unsigned int gu32;
typedef __attribute__((address_space(3))) unsigned int lu32;

__device__ __forceinline__ void gload_lds16(const void* g, void* l) {
  __builtin_amdgcn_global_load_lds((gu32*)g, (lu32*)l, 16, 0, 0);
}

__device__ __forceinline__ ushort f2bf(float f) {
  __hip_bfloat16 b = __float2bfloat16(f);
  return *reinterpret_cast<ushort*>(&b);
}

__device__ __forceinline__ short8 cvt8(float4 a, float4 b) {
  union { short8 v; ushort u[8]; } p;
  p.u[0] = f2bf(a.x); p.u[1] = f2bf(a.y); p.u[2] = f2bf(a.z); p.u[3] = f2bf(a.w);
  p.u[4] = f2bf(b.x); p.u[5] = f2bf(b.y); p.u[6] = f2bf(b.z); p.u[7] = f2bf(b.w);
  return p.v;
}

// ---- pack weights into per-K-step LDS fragment image: [t][kg][col][j] -------
__global__ void k_prepB(const float* __restrict__ Wres, const float* __restrict__ W1,
                        ushort* __restrict__ Bp) {
  int i = blockIdx.x * 256 + threadIdx.x;          // i = (t*4+kg)*128 + col
  if (i >= KSTEPS * 4 * 128) return;
  int col = i & 127;
  int kbase = (i >> 7) * 8;
  const float* W = (col < 64) ? Wres : W1;
  int c = col & 63;
  union { short8 v; ushort u[8]; } p;
#pragma unroll
  for (int j = 0; j < 8; ++j) {
    int k = kbase + j;
    p.u[j] = f2bf(k < NUM_FEAT ? W[(size_t)k * 64 + c] : 0.f);
  }
  *(short8*)&Bp[(size_t)i * 8] = p.v;
}

// ---- MFMA GEMM: H[n][0:64] = x@w_res + b_res ; H[n][64:128] = x@w1 ----------
__global__ __launch_bounds__(256) void k_gemm_mfma(const float* __restrict__ X,
    const ushort* __restrict__ Bp, const float* __restrict__ brs,
    float* __restrict__ H) {
  __shared__ ushort ldsB[2][4096];                 // [buf][kg*128+col][8]
  const int tid = threadIdx.x;
  const int lane = tid & 63, wid = tid >> 6;
  const int lg = lane >> 4, lr = lane & 15;
  const int m0 = blockIdx.x * 64;

  int rowg = m0 + wid * 16 + lr;
  rowg = rowg < N_NODES ? rowg : N_NODES - 1;
  const float* axp = X + (size_t)rowg * NUM_FEAT + lg * 8;

  f32x4 acc[8] = {};
  float4 a0, a1, na0, na1;
  const float4 fz = make_float4(0.f, 0.f, 0.f, 0.f);

  auto loadA = [&](int t, float4& r0, float4& r1) {
    int k0 = t * 32 + lg * 8;
    if (k0 < NUM_FEAT) {
      r0 = *(const float4*)(axp + t * 32);
      r1 = *(const float4*)(axp + t * 32 + 4);
    } else { r0 = fz; r1 = fz; }
  };
  auto stageB = [&](int t, int buf) {
    const ushort* g0 = Bp + (size_t)t * 4096 + (size_t)(wid * 64 + lane) * 8;
    gload_lds16(g0, &ldsB[buf][(size_t)(wid * 64) * 8]);
    gload_lds16(g0 + 2048, &ldsB[buf][(size_t)(256 + wid * 64) * 8]);
  };

  stageB(0, 0);
  loadA(0, a0, a1);
  __syncthreads();

  for (int t = 0; t < KSTEPS - 1; ++t) {
    const int cur = t & 1, nxt = cur ^ 1;
    stageB(t + 1, nxt);
    short8 fb[8];
#pragma unroll
    for (int n = 0; n < 8; ++n)
      fb[n] = *(const short8*)&ldsB[cur][(size_t)(lg * 128 + n * 16 + lr) * 8];
    loadA(t + 1, na0, na1);
    short8 fa = cvt8(a0, a1);
#pragma unroll
    for (int n = 0; n < 8; ++n)
      acc[n] = __builtin_amdgcn_mfma_f32_16x16x32_bf16(fa, fb[n], acc[n], 0, 0, 0);
    a0 = na0; a1 = na1;
    __syncthreads();
  }
  {
    const int cur = (KSTEPS - 1) & 1;
    short8 fb[8];
#pragma unroll
    for (int n = 0; n < 8; ++n)
      fb[n] = *(const short8*)&ldsB[cur][(size_t)(lg * 128 + n * 16 + lr) * 8];
    short8 fa = cvt8(a0, a1);
#pragma unroll
    for (int n = 0; n < 8; ++n)
      acc[n] = __builtin_amdgcn_mfma_f32_16x16x32_bf16(fa, fb[n], acc[n], 0, 0, 0);
  }

#pragma unroll
  for (int n = 0; n < 8; ++n) {
    int col = n * 16 + lr;
    float badd = (col < 64) ? brs[col] : 0.f;
#pragma unroll
    for (int i = 0; i < 4; ++i) {
      int row = m0 + wid * 16 + lg * 4 + i;
      if (row < N_NODES) H[(size_t)row * 128 + col] = acc[n][i] + badd;
    }
  }
}

// ---------------- per-node attention logits for layer 1 ---------------------
__global__ void k_attn1(const float* __restrict__ H, const float* __restrict__ att_src,
                        const float* __restrict__ att_dst, float* __restrict__ a_src,
                        float* __restrict__ a_dst) {
  int i = blockIdx.x * blockDim.x + threadIdx.x;  // i = n*8 + h
  if (i >= N_NODES * HEADS) return;
  int h = i & 7;
  const float* hp = &H[(size_t)(i >> 3) * 128 + 64 + h * 8];
  float s = 0.f, d = 0.f;
#pragma unroll
  for (int c = 0; c < 8; ++c) {
    float v = hp[c];
    s = fmaf(v, att_src[h * 8 + c], s);
    d = fmaf(v, att_dst[h * 8 + c], d);
  }
  a_src[i] = s; a_dst[i] = d;
}

// ---------------- CSR build (by dst): degree, 3-phase scan, fill ------------
__global__ void k_degree(const int* __restrict__ ei, int* __restrict__ deg) {
  int e = blockIdx.x * blockDim.x + threadIdx.x;
  if (e >= E_TOTAL) return;
  int d = e < NUM_EDGES ? ei[NUM_EDGES + e] : e - NUM_EDGES;
  atomicAdd(&deg[d], 1);
}

__global__ __launch_bounds__(256) void k_bsum(const int* __restrict__ deg,
                                              int* __restrict__ bsum) {
  __shared__ int sm[256];
  int t = threadIdx.x, i = blockIdx.x * 256 + t;
  sm[t] = (i < N_NODES) ? deg[i] : 0;
  __syncthreads();
  for (int off = 128; off > 0; off >>= 1) {
    if (t < off) sm[t] += sm[t + off];
    __syncthreads();
  }
  if (t == 0) bsum[blockIdx.x] = sm[0];
}

__global__ __launch_bounds__(256) void k_bscan(const int* __restrict__ bsum,
                                               int* __restrict__ boff) {
  __shared__ int sm[256];
  int t = threadIdx.x;
  int own = (t < SCAN_BLOCKS) ? bsum[t] : 0;
  sm[t] = own;
  __syncthreads();
  for (int off = 1; off < 256; off <<= 1) {
    int add = (t >= off) ? sm[t - off] : 0;
    __syncthreads();
    sm[t] += add;
    __syncthreads();
  }
  if (t < SCAN_BLOCKS) boff[t] = sm[t] - own;   // exclusive
}

__global__ __launch_bounds__(256) void k_blocal(const int* __restrict__ deg,
    const int* __restrict__ boff, int* __restrict__ rowptr) {
  __shared__ int sm[256];
  int t = threadIdx.x, b = blockIdx.x, i = b * 256 + t;
  int v = (i < N_NODES) ? deg[i] : 0;
  sm[t] = v;
  __syncthreads();
  for (int off = 1; off < 256; off <<= 1) {
    int add = (t >= off) ? sm[t - off] : 0;
    __syncthreads();
    sm[t] += add;
    __syncthreads();
  }
  if (i < N_NODES) rowptr[i + 1] = boff[b] + sm[t];
  if (i == 0) rowptr[0] = 0;
}

__global__ void k_fill(const int* __restrict__ ei, const int* __restrict__ rowptr,
                       int* __restrict__ cursor, int* __restrict__ eid) {
  int e = blockIdx.x * blockDim.x + threadIdx.x;
  if (e >= E_TOTAL) return;
  int d = e < NUM_EDGES ? ei[NUM_EDGES + e] : e - NUM_EDGES;
  int pos = atomicAdd(&cursor[d], 1);
  eid[rowptr[d] + pos] = e;
}

// ---------------- layer-1 aggregation: one wave per node, lane = (head*8+c) --
__global__ __launch_bounds__(256) void k_layer1(const int* __restrict__ ei,
    const int* __restrict__ rowptr, const int* __restrict__ eid,
    const float* __restrict__ H, const float* __restrict__ a_src,
    const float* __restrict__ a_dst, const float* __restrict__ b1,
    float* __restrict__ x1, float* __restrict__ alpha1) {
  int wave = threadIdx.x >> 6, lane = threadIdx.x & 63;
  int n = blockIdx.x * 4 + wave;
  if (n >= N_NODES) return;
  int hd = lane >> 3;
  float adn = a_dst[n * 8 + hd];
  int start = rowptr[n], end = rowptr[n + 1];
  float denom = 0.f, msg = 0.f;
  // 8 edges in flight per iteration: independent eid->ei->gather chains
  for (int p = start; p < end; p += 8) {
    int s8[8];
#pragma unroll
    for (int i = 0; i < 8; ++i) {
      int idx = p + i; idx = idx < end ? idx : end - 1;
      int e = eid[idx];
      s8[i] = e < NUM_EDGES ? ei[e] : e - NUM_EDGES;
    }
    float av[8], hv[8];
#pragma unroll
    for (int i = 0; i < 8; ++i) {
      av[i] = a_src[s8[i] * 8 + hd];
      hv[i] = H[(size_t)s8[i] * 128 + 64 + lane];
    }
#pragma unroll
    for (int i = 0; i < 8; ++i) {
      if (p + i < end) {
        float sc = av[i] + adn;
        sc = sc > 0.f ? sc : 0.2f * sc;
        float ev = __expf(sc);
        denom += ev;
        msg = fmaf(ev, hv[i], msg);
      }
    }
  }
  float invd = 1.f / (denom + 1e-16f);
  float h1v = msg * invd + b1[lane];
  float x1v = h1v + H[(size_t)n * 128 + lane];   // residual part
  x1v = x1v > 0.f ? x1v : __expf(x1v) - 1.f;     // elu
  x1[(size_t)n * 64 + lane] = x1v;

  // alpha writes: 16 edges per iteration (2x8), lane -> (edge off lane>>3, head lane&7)
  int h8 = lane & 7;
  int eo = lane >> 3;
  float invh = __shfl(invd, h8 * 8);
  float adh = a_dst[n * 8 + h8];
  for (int p = start; p < end; p += 16) {
    int i0 = p + eo, i1 = p + 8 + eo;
    bool v0 = i0 < end, v1 = i1 < end;
    int e0 = v0 ? eid[i0] : 0;
    int e1 = v1 ? eid[i1] : 0;
    int s0 = e0 < NUM_EDGES ? ei[e0] : e0 - NUM_EDGES;
    int s1 = e1 < NUM_EDGES ? ei[e1] : e1 - NUM_EDGES;
    if (v0) {
      float sc = a_src[s0 * 8 + h8] + adh;
      sc = sc > 0.f ? sc : 0.2f * sc;
      alpha1[(size_t)e0 * 8 + h8] = __expf(sc) * invh;
    }
    if (v1) {
      float sc = a_src[s1 * 8 + h8] + adh;
      sc = sc > 0.f ? sc : 0.2f * sc;
      alpha1[(size_t)e1 * 8 + h8] = __expf(sc) * invh;
    }
  }
}

// ---------------- layer-2 prep: h2 = x1 @ w2 (+attn logits) -----------------
__global__ __launch_bounds__(256) void k_layer2prep(const float* __restrict__ x1,
    const float* __restrict__ w2, const float* __restrict__ att_src2,
    const float* __restrict__ att_dst2, float* __restrict__ h2p,
    float* __restrict__ a_src2, float* __restrict__ a_dst2) {
  __shared__ float w2s[64 * 30];
  for (int i = threadIdx.x; i < 64 * 30; i += 256) w2s[i] = w2[i];
  __syncthreads();
  int wave = threadIdx.x >> 6, lane = threadIdx.x & 63;
  int n = blockIdx.x * 4 + wave;
  if (n >= N_NODES) return;
  float acc = 0.f;
  const float* xr = &x1[(size_t)n * 64];
  if (lane < 30) {
#pragma unroll 8
    for (int k = 0; k < 64; ++k) acc = fmaf(xr[k], w2s[k * 30 + lane], acc);
  }
  float as = (lane < 30) ? acc * att_src2[lane] : 0.f;
  float ad = (lane < 30) ? acc * att_dst2[lane] : 0.f;
  for (int off = 1; off < 64; off <<= 1) {
    as += __shfl_xor(as, off);
    ad += __shfl_xor(ad, off);
  }
  if (lane == 0) { a_src2[n] = as; a_dst2[n] = ad; }
  if (lane < 32) h2p[(size_t)n * 32 + lane] = (lane < 30) ? acc : 0.f;
}

// ---------------- layer-2 aggregation + elu + log_softmax + alpha2 ----------
__global__ __launch_bounds__(256) void k_layer2(const int* __restrict__ ei,
    const int* __restrict__ rowptr, const int* __restrict__ eid,
    const float* __restrict__ h2p, const float* __restrict__ a_src2,
    const float* __restrict__ a_dst2, const float* __restrict__ b2,
    float* __restrict__ out0, float* __restrict__ alpha2) {
  int wave = threadIdx.x >> 6, lane = threadIdx.x & 63;
  int n = blockIdx.x * 4 + wave;
  if (n >= N_NODES) return;
  float adn = a_dst2[n];
  int start = rowptr[n], end = rowptr[n + 1];
  int half = lane >> 5, cls = lane & 31;
  float denom = 0.f, msg = 0.f;
  for (int p = start; p < end; p += 2) {
    int idx = p + half;
    bool valid = idx < end;
    idx = valid ? idx : end - 1;
    int e = eid[idx];
    int s = e < NUM_EDGES ? ei[e] : e - NUM_EDGES;
    float asv = a_src2[s];
    float hvv = h2p[(size_t)s * 32 + cls];
    if (valid) {
      float sc = asv + adn;
      sc = sc > 0.f ? sc : 0.2f * sc;
      float ev = __expf(sc);
      denom += ev;
      msg = fmaf(ev, hvv, msg);
    }
  }
  denom += __shfl_xor(denom, 32);
  msg   += __shfl_xor(msg, 32);
  float invd = 1.f / (denom + 1e-16f);
  bool act = lane < 30;
  float o = act ? msg * invd + b2[lane] : 0.f;
  float x2 = o > 0.f ? o : __expf(o) - 1.f;
  float mv = act ? x2 : -1e30f;
  for (int off = 1; off < 64; off <<= 1) mv = fmaxf(mv, __shfl_xor(mv, off));
  float ex = act ? __expf(x2 - mv) : 0.f;
  for (int off = 1; off < 64; off <<= 1) ex += __shfl_xor(ex, off);
  if (act) out0[(size_t)n * 30 + lane] = x2 - mv - __logf(ex);
  for (int p = start; p < end; p += 64) {
    int idx = p + lane;
    if (idx < end) {
      int e = eid[idx];
      int s = e < NUM_EDGES ? ei[e] : e - NUM_EDGES;
      float sc = a_src2[s] + adn;
      sc = sc > 0.f ? sc : 0.2f * sc;
      alpha2[e] = __expf(sc) * invd;
    }
  }
}

extern "C" void kernel_launch(void* const* d_in, const int* in_sizes, int n_in,
                              void* d_out, int out_size, void* d_ws, size_t ws_size,
                              hipStream_t stream) {
  const float* x        = (const float*)d_in[0];
  const int*   ei       = (const int*)d_in[1];
  const float* w_res    = (const float*)d_in[2];
  const float* b_res    = (const float*)d_in[3];
  const float* w1       = (const float*)d_in[4];
  const float* att_src1 = (const float*)d_in[5];
  const float* att_dst1 = (const float*)d_in[6];
  const float* b1       = (const float*)d_in[7];
  const float* w2       = (const float*)d_in[8];
  const float* att_src2 = (const float*)d_in[9];
  const float* att_dst2 = (const float*)d_in[10];
  const float* b2       = (const float*)d_in[11];

  float* ws = (float*)d_ws;
  float* H       = ws;                                  // [N][128]
  float* a_src1  = H + (size_t)N_NODES * 128;           // [N][8]
  float* a_dst1  = a_src1 + (size_t)N_NODES * 8;        // [N][8]
  float* x1      = a_dst1 + (size_t)N_NODES * 8;        // [N][64]
  float* h2p     = x1 + (size_t)N_NODES * 64;           // [N][32]
  float* a_src2  = h2p + (size_t)N_NODES * 32;          // [N]
  float* a_dst2  = a_src2 + N_NODES;                    // [N]
  int*   deg     = (int*)(a_dst2 + N_NODES);            // [N]
  int*   rowptr  = deg + N_NODES;                       // [N+1] (pad)
  int*   cursor  = rowptr + N_NODES + 16;               // [N]
  int*   eid     = cursor + N_NODES;                    // [E_TOTAL]
  int*   bsum    = eid + E_TOTAL;                       // [SCAN_BLOCKS]
  int*   boff    = bsum + SCAN_BLOCKS + 16;             // [SCAN_BLOCKS]
  ushort* Bp     = (ushort*)x1;                         // aliases x1 (dead then)

  float* out0   = (float*)d_out;                        // [N][30]
  float* alpha1 = out0 + (size_t)N_NODES * 30;          // [E_TOTAL][8]
  float* alpha2 = alpha1 + (size_t)E_TOTAL * 8;         // [E_TOTAL]

  hipMemsetAsync(deg, 0, N_NODES * sizeof(int), stream);
  hipMemsetAsync(cursor, 0, N_NODES * sizeof(int), stream);

  k_prepB<<<(KSTEPS * 4 * 128 + 255) / 256, 256, 0, stream>>>(w_res, w1, Bp);
  k_gemm_mfma<<<(N_NODES + 63) / 64, 256, 0, stream>>>(x, Bp, b_res, H);
  k_attn1<<<(N_NODES * HEADS + 255) / 256, 256, 0, stream>>>(H, att_src1, att_dst1,
                                                             a_src1, a_dst1);
  k_degree<<<(E_TOTAL + 255) / 256, 256, 0, stream>>>(ei, deg);
  k_bsum<<<SCAN_BLOCKS, 256, 0, stream>>>(deg, bsum);
  k_bscan<<<1, 256, 0, stream>>>(bsum, boff);
  k_blocal<<<SCAN_BLOCKS, 256, 0, stream>>>(deg, boff, rowptr);
  k_fill<<<(E_TOTAL + 255) / 256, 256, 0, stream>>>(ei, rowptr, cursor, eid);
  k_layer1<<<(N_NODES + 3) / 4, 256, 0, stream>>>(ei, rowptr, eid, H, a_src1, a_dst1,
                                                  b1, x1, alpha1);
  k_layer2prep<<<(N_NODES + 3) / 4, 256, 0, stream>>>(x1, w2, att_src2, att_dst2,
                                                      h2p, a_src2, a_dst2);
  k_layer2<<<(N_NODES + 3) / 4, 256, 0, stream>>>(ei, rowptr, eid, h2p, a_src2,
                                                  a_dst2, b2, out0, alpha2);
}

// Round 5
// 643.950 us; speedup vs baseline: 2.0458x; 1.0654x over previous
//
#include <hip/hip_runtime.h>
#include <hip/hip_bf16.h>

#define N_NODES 50000
#define NUM_FEAT 2000
#define HEADS 8
#define HID 8
#define NUM_CLASSES 30
#define NUM_EDGES 1600000
#define E_TOTAL (NUM_EDGES + N_NODES)
#define KSTEPS 63   // ceil(2000/32)
#define SCAN_BLOCKS ((N_NODES + 255) / 256)   // 196

typedef __attribute__((ext_vector_type(8))) short short8;
typedef __attribute__((ext_vector_type(4))) float f32x4;

typedef __attribute__((address_space(1))) const unsigned int gu32;
typedef __attribute__((address_space(3))) unsigned int lu32;

__device__ __forceinline__ void gload_lds16(const void* g, void* l) {
  __builtin_amdgcn_global_load_lds((gu32*)g, (lu32*)l, 16, 0, 0);
}

__device__ __forceinline__ ushort f2bf(float f) {
  __hip_bfloat16 b = __float2bfloat16(f);
  return *reinterpret_cast<ushort*>(&b);
}

__device__ __forceinline__ float bf2f(ushort u) {
  unsigned int x = ((unsigned int)u) << 16;
  union { unsigned int i; float f; } c; c.i = x;
  return c.f;
}

__device__ __forceinline__ short8 cvt8(float4 a, float4 b) {
  union { short8 v; ushort u[8]; } p;
  p.u[0] = f2bf(a.x); p.u[1] = f2bf(a.y); p.u[2] = f2bf(a.z); p.u[3] = f2bf(a.w);
  p.u[4] = f2bf(b.x); p.u[5] = f2bf(b.y); p.u[6] = f2bf(b.z); p.u[7] = f2bf(b.w);
  return p.v;
}

// ---- pack weights into per-K-step LDS fragment image: [t][kg][col][j] -------
__global__ void k_prepB(const float* __restrict__ Wres, const float* __restrict__ W1,
                        ushort* __restrict__ Bp) {
  int i = blockIdx.x * 256 + threadIdx.x;          // i = (t*4+kg)*128 + col
  if (i >= KSTEPS * 4 * 128) return;
  int col = i & 127;
  int kbase = (i >> 7) * 8;
  const float* W = (col < 64) ? Wres : W1;
  int c = col & 63;
  union { short8 v; ushort u[8]; } p;
#pragma unroll
  for (int j = 0; j < 8; ++j) {
    int k = kbase + j;
    p.u[j] = f2bf(k < NUM_FEAT ? W[(size_t)k * 64 + c] : 0.f);
  }
  *(short8*)&Bp[(size_t)i * 8] = p.v;
}

// ---- MFMA GEMM: Hres[n][0:64] = x@w_res + b_res (f32); Hatt = x@w1 (bf16) ---
__global__ __launch_bounds__(256) void k_gemm_mfma(const float* __restrict__ X,
    const ushort* __restrict__ Bp, const float* __restrict__ brs,
    float* __restrict__ Hres, ushort* __restrict__ Hatt) {
  __shared__ ushort ldsB[2][4096];                 // [buf][kg*128+col][8]
  const int tid = threadIdx.x;
  const int lane = tid & 63, wid = tid >> 6;
  const int lg = lane >> 4, lr = lane & 15;
  const int m0 = blockIdx.x * 64;

  int rowg = m0 + wid * 16 + lr;
  rowg = rowg < N_NODES ? rowg : N_NODES - 1;
  const float* axp = X + (size_t)rowg * NUM_FEAT + lg * 8;

  f32x4 acc[8] = {};
  float4 a0, a1, na0, na1;
  const float4 fz = make_float4(0.f, 0.f, 0.f, 0.f);

  auto loadA = [&](int t, float4& r0, float4& r1) {
    int k0 = t * 32 + lg * 8;
    if (k0 < NUM_FEAT) {
      r0 = *(const float4*)(axp + t * 32);
      r1 = *(const float4*)(axp + t * 32 + 4);
    } else { r0 = fz; r1 = fz; }
  };
  auto stageB = [&](int t, int buf) {
    const ushort* g0 = Bp + (size_t)t * 4096 + (size_t)(wid * 64 + lane) * 8;
    gload_lds16(g0, &ldsB[buf][(size_t)(wid * 64) * 8]);
    gload_lds16(g0 + 2048, &ldsB[buf][(size_t)(256 + wid * 64) * 8]);
  };

  stageB(0, 0);
  loadA(0, a0, a1);
  __syncthreads();

  for (int t = 0; t < KSTEPS - 1; ++t) {
    const int cur = t & 1, nxt = cur ^ 1;
    stageB(t + 1, nxt);
    short8 fb[8];
#pragma unroll
    for (int n = 0; n < 8; ++n)
      fb[n] = *(const short8*)&ldsB[cur][(size_t)(lg * 128 + n * 16 + lr) * 8];
    loadA(t + 1, na0, na1);
    short8 fa = cvt8(a0, a1);
#pragma unroll
    for (int n = 0; n < 8; ++n)
      acc[n] = __builtin_amdgcn_mfma_f32_16x16x32_bf16(fa, fb[n], acc[n], 0, 0, 0);
    a0 = na0; a1 = na1;
    __syncthreads();
  }
  {
    const int cur = (KSTEPS - 1) & 1;
    short8 fb[8];
#pragma unroll
    for (int n = 0; n < 8; ++n)
      fb[n] = *(const short8*)&ldsB[cur][(size_t)(lg * 128 + n * 16 + lr) * 8];
    short8 fa = cvt8(a0, a1);
#pragma unroll
    for (int n = 0; n < 8; ++n)
      acc[n] = __builtin_amdgcn_mfma_f32_16x16x32_bf16(fa, fb[n], acc[n], 0, 0, 0);
  }

  // epilogue: C/D map col=lane&15, row=(lane>>4)*4+i  [m89-verified]
#pragma unroll
  for (int n = 0; n < 8; ++n) {
    int col = n * 16 + lr;
    if (col < 64) {
      float badd = brs[col];
#pragma unroll
      for (int i = 0; i < 4; ++i) {
        int row = m0 + wid * 16 + lg * 4 + i;
        if (row < N_NODES) Hres[(size_t)row * 64 + col] = acc[n][i] + badd;
      }
    } else {
#pragma unroll
      for (int i = 0; i < 4; ++i) {
        int row = m0 + wid * 16 + lg * 4 + i;
        if (row < N_NODES) Hatt[(size_t)row * 64 + (col - 64)] = f2bf(acc[n][i]);
      }
    }
  }
}

// ---------------- per-node attention logits for layer 1 ---------------------
__global__ void k_attn1(const ushort* __restrict__ Hatt, const float* __restrict__ att_src,
                        const float* __restrict__ att_dst, float* __restrict__ a_src,
                        float* __restrict__ a_dst) {
  int i = blockIdx.x * blockDim.x + threadIdx.x;  // i = n*8 + h
  if (i >= N_NODES * HEADS) return;
  int h = i & 7;
  const ushort* hp = &Hatt[(size_t)(i >> 3) * 64 + h * 8];
  float s = 0.f, d = 0.f;
#pragma unroll
  for (int c = 0; c < 8; ++c) {
    float v = bf2f(hp[c]);
    s = fmaf(v, att_src[h * 8 + c], s);
    d = fmaf(v, att_dst[h * 8 + c], d);
  }
  a_src[i] = s; a_dst[i] = d;
}

// ---------------- CSR build (by dst): degree, 3-phase scan, fill ------------
__global__ void k_degree(const int* __restrict__ ei, int* __restrict__ deg) {
  int e = blockIdx.x * blockDim.x + threadIdx.x;
  if (e >= E_TOTAL) return;
  int d = e < NUM_EDGES ? ei[NUM_EDGES + e] : e - NUM_EDGES;
  atomicAdd(&deg[d], 1);
}

__global__ __launch_bounds__(256) void k_bsum(const int* __restrict__ deg,
                                              int* __restrict__ bsum) {
  __shared__ int sm[256];
  int t = threadIdx.x, i = blockIdx.x * 256 + t;
  sm[t] = (i < N_NODES) ? deg[i] : 0;
  __syncthreads();
  for (int off = 128; off > 0; off >>= 1) {
    if (t < off) sm[t] += sm[t + off];
    __syncthreads();
  }
  if (t == 0) bsum[blockIdx.x] = sm[0];
}

__global__ __launch_bounds__(256) void k_bscan(const int* __restrict__ bsum,
                                               int* __restrict__ boff) {
  __shared__ int sm[256];
  int t = threadIdx.x;
  int own = (t < SCAN_BLOCKS) ? bsum[t] : 0;
  sm[t] = own;
  __syncthreads();
  for (int off = 1; off < 256; off <<= 1) {
    int add = (t >= off) ? sm[t - off] : 0;
    __syncthreads();
    sm[t] += add;
    __syncthreads();
  }
  if (t < SCAN_BLOCKS) boff[t] = sm[t] - own;   // exclusive
}

__global__ __launch_bounds__(256) void k_blocal(const int* __restrict__ deg,
    const int* __restrict__ boff, int* __restrict__ rowptr) {
  __shared__ int sm[256];
  int t = threadIdx.x, b = blockIdx.x, i = b * 256 + t;
  int v = (i < N_NODES) ? deg[i] : 0;
  sm[t] = v;
  __syncthreads();
  for (int off = 1; off < 256; off <<= 1) {
    int add = (t >= off) ? sm[t - off] : 0;
    __syncthreads();
    sm[t] += add;
    __syncthreads();
  }
  if (i < N_NODES) rowptr[i + 1] = boff[b] + sm[t];
  if (i == 0) rowptr[0] = 0;
}

__global__ void k_fill(const int* __restrict__ ei, const int* __restrict__ rowptr,
                       int* __restrict__ cursor, int* __restrict__ eid) {
  int e = blockIdx.x * blockDim.x + threadIdx.x;
  if (e >= E_TOTAL) return;
  int d = e < NUM_EDGES ? ei[NUM_EDGES + e] : e - NUM_EDGES;
  int pos = atomicAdd(&cursor[d], 1);
  eid[rowptr[d] + pos] = e;
}

// ---------------- layer-1 aggregation: one wave per node, lane = (head*8+c) --
__global__ __launch_bounds__(256) void k_layer1(const int* __restrict__ ei,
    const int* __restrict__ rowptr, const int* __restrict__ eid,
    const float* __restrict__ Hres, const ushort* __restrict__ Hatt,
    const float* __restrict__ a_src, const float* __restrict__ a_dst,
    const float* __restrict__ b1, float* __restrict__ x1,
    float* __restrict__ alpha1) {
  int wave = threadIdx.x >> 6, lane = threadIdx.x & 63;
  int n = blockIdx.x * 4 + wave;
  if (n >= N_NODES) return;
  int hd = lane >> 3;
  float adn = a_dst[n * 8 + hd];
  int start = rowptr[n], end = rowptr[n + 1];
  float denom = 0.f, msg = 0.f;
  // 8 edges in flight per iteration: independent eid->ei->gather chains
  for (int p = start; p < end; p += 8) {
    int s8[8];
#pragma unroll
    for (int i = 0; i < 8; ++i) {
      int idx = p + i; idx = idx < end ? idx : end - 1;
      int e = eid[idx];
      s8[i] = e < NUM_EDGES ? ei[e] : e - NUM_EDGES;
    }
    float av[8];
    ushort hu[8];
#pragma unroll
    for (int i = 0; i < 8; ++i) {
      av[i] = a_src[s8[i] * 8 + hd];
      hu[i] = Hatt[(size_t)s8[i] * 64 + lane];
    }
#pragma unroll
    for (int i = 0; i < 8; ++i) {
      if (p + i < end) {
        float sc = av[i] + adn;
        sc = sc > 0.f ? sc : 0.2f * sc;
        float ev = __expf(sc);
        denom += ev;
        msg = fmaf(ev, bf2f(hu[i]), msg);
      }
    }
  }
  float invd = 1.f / (denom + 1e-16f);
  float h1v = msg * invd + b1[lane];
  float x1v = h1v + Hres[(size_t)n * 64 + lane];   // residual part
  x1v = x1v > 0.f ? x1v : __expf(x1v) - 1.f;       // elu
  x1[(size_t)n * 64 + lane] = x1v;

  // alpha writes: 16 edges per iteration (2x8), lane -> (edge off lane>>3, head lane&7)
  int h8 = lane & 7;
  int eo = lane >> 3;
  float invh = __shfl(invd, h8 * 8);
  float adh = a_dst[n * 8 + h8];
  for (int p = start; p < end; p += 16) {
    int i0 = p + eo, i1 = p + 8 + eo;
    bool v0 = i0 < end, v1 = i1 < end;
    int e0 = v0 ? eid[i0] : 0;
    int e1 = v1 ? eid[i1] : 0;
    int s0 = e0 < NUM_EDGES ? ei[e0] : e0 - NUM_EDGES;
    int s1 = e1 < NUM_EDGES ? ei[e1] : e1 - NUM_EDGES;
    if (v0) {
      float sc = a_src[s0 * 8 + h8] + adh;
      sc = sc > 0.f ? sc : 0.2f * sc;
      alpha1[(size_t)e0 * 8 + h8] = __expf(sc) * invh;
    }
    if (v1) {
      float sc = a_src[s1 * 8 + h8] + adh;
      sc = sc > 0.f ? sc : 0.2f * sc;
      alpha1[(size_t)e1 * 8 + h8] = __expf(sc) * invh;
    }
  }
}

// ---------------- layer-2 prep: h2 = x1 @ w2 (+attn logits), bf16 table -----
__global__ __launch_bounds__(256) void k_layer2prep(const float* __restrict__ x1,
    const float* __restrict__ w2, const float* __restrict__ att_src2,
    const float* __restrict__ att_dst2, ushort* __restrict__ h2b,
    float* __restrict__ a_src2, float* __restrict__ a_dst2) {
  __shared__ float w2s[64 * 30];
  for (int i = threadIdx.x; i < 64 * 30; i += 256) w2s[i] = w2[i];
  __syncthreads();
  int wave = threadIdx.x >> 6, lane = threadIdx.x & 63;
  int n = blockIdx.x * 4 + wave;
  if (n >= N_NODES) return;
  float acc = 0.f;
  const float* xr = &x1[(size_t)n * 64];
  if (lane < 30) {
#pragma unroll 8
    for (int k = 0; k < 64; ++k) acc = fmaf(xr[k], w2s[k * 30 + lane], acc);
  }
  float as = (lane < 30) ? acc * att_src2[lane] : 0.f;
  float ad = (lane < 30) ? acc * att_dst2[lane] : 0.f;
  for (int off = 1; off < 64; off <<= 1) {
    as += __shfl_xor(as, off);
    ad += __shfl_xor(ad, off);
  }
  if (lane == 0) { a_src2[n] = as; a_dst2[n] = ad; }
  if (lane < 32) h2b[(size_t)n * 32 + lane] = (lane < 30) ? f2bf(acc) : (ushort)0;
}

// ---------------- layer-2 aggregation + elu + log_softmax + alpha2 ----------
__global__ __launch_bounds__(256) void k_layer2(const int* __restrict__ ei,
    const int* __restrict__ rowptr, const int* __restrict__ eid,
    const ushort* __restrict__ h2b, const float* __restrict__ a_src2,
    const float* __restrict__ a_dst2, const float* __restrict__ b2,
    float* __restrict__ out0, float* __restrict__ alpha2) {
  int wave = threadIdx.x >> 6, lane = threadIdx.x & 63;
  int n = blockIdx.x * 4 + wave;
  if (n >= N_NODES) return;
  float adn = a_dst2[n];
  int start = rowptr[n], end = rowptr[n + 1];
  int half = lane >> 5, cls = lane & 31;
  float denom = 0.f, msg = 0.f;
  // 2x unroll: 4 edges in flight (2 per 32-lane half)
  for (int p = start; p < end; p += 4) {
    int idx0 = p + half, idx1 = p + 2 + half;
    bool vl0 = idx0 < end, vl1 = idx1 < end;
    int j0 = vl0 ? idx0 : end - 1;
    int j1 = vl1 ? idx1 : end - 1;
    int e0 = eid[j0], e1 = eid[j1];
    int s0 = e0 < NUM_EDGES ? ei[e0] : e0 - NUM_EDGES;
    int s1 = e1 < NUM_EDGES ? ei[e1] : e1 - NUM_EDGES;
    float as0 = a_src2[s0], as1 = a_src2[s1];
    ushort hv0 = h2b[(size_t)s0 * 32 + cls];
    ushort hv1 = h2b[(size_t)s1 * 32 + cls];
    if (vl0) {
      float sc = as0 + adn;
      sc = sc > 0.f ? sc : 0.2f * sc;
      float ev = __expf(sc);
      denom += ev;
      msg = fmaf(ev, bf2f(hv0), msg);
    }
    if (vl1) {
      float sc = as1 + adn;
      sc = sc > 0.f ? sc : 0.2f * sc;
      float ev = __expf(sc);
      denom += ev;
      msg = fmaf(ev, bf2f(hv1), msg);
    }
  }
  denom += __shfl_xor(denom, 32);
  msg   += __shfl_xor(msg, 32);
  float invd = 1.f / (denom + 1e-16f);
  bool act = lane < 30;
  float o = act ? msg * invd + b2[lane] : 0.f;
  float x2 = o > 0.f ? o : __expf(o) - 1.f;
  float mv = act ? x2 : -1e30f;
  for (int off = 1; off < 64; off <<= 1) mv = fmaxf(mv, __shfl_xor(mv, off));
  float ex = act ? __expf(x2 - mv) : 0.f;
  for (int off = 1; off < 64; off <<= 1) ex += __shfl_xor(ex, off);
  if (act) out0[(size_t)n * 30 + lane] = x2 - mv - __logf(ex);
  for (int p = start; p < end; p += 64) {
    int idx = p + lane;
    if (idx < end) {
      int e = eid[idx];
      int s = e < NUM_EDGES ? ei[e] : e - NUM_EDGES;
      float sc = a_src2[s] + adn;
      sc = sc > 0.f ? sc : 0.2f * sc;
      alpha2[e] = __expf(sc) * invd;
    }
  }
}

extern "C" void kernel_launch(void* const* d_in, const int* in_sizes, int n_in,
                              void* d_out, int out_size, void* d_ws, size_t ws_size,
                              hipStream_t stream) {
  const float* x        = (const float*)d_in[0];
  const int*   ei       = (const int*)d_in[1];
  const float* w_res    = (const float*)d_in[2];
  const float* b_res    = (const float*)d_in[3];
  const float* w1       = (const float*)d_in[4];
  const float* att_src1 = (const float*)d_in[5];
  const float* att_dst1 = (const float*)d_in[6];
  const float* b1       = (const float*)d_in[7];
  const float* w2       = (const float*)d_in[8];
  const float* att_src2 = (const float*)d_in[9];
  const float* att_dst2 = (const float*)d_in[10];
  const float* b2       = (const float*)d_in[11];

  float* ws = (float*)d_ws;
  float* Hres    = ws;                                  // [N][64] f32
  float* x1      = Hres + (size_t)N_NODES * 64;         // [N][64] f32
  float* a_src1  = x1 + (size_t)N_NODES * 64;           // [N][8]
  float* a_dst1  = a_src1 + (size_t)N_NODES * 8;        // [N][8]
  float* a_src2  = a_dst1 + (size_t)N_NODES * 8;        // [N]
  float* a_dst2  = a_src2 + N_NODES;                    // [N]
  ushort* Hatt   = (ushort*)(a_dst2 + N_NODES);         // [N][64] bf16
  ushort* h2b    = Hatt + (size_t)N_NODES * 64;         // [N][32] bf16
  int*   deg     = (int*)(h2b + (size_t)N_NODES * 32);  // [N]
  int*   rowptr  = deg + N_NODES;                       // [N+1] (pad)
  int*   cursor  = rowptr + N_NODES + 16;               // [N]
  int*   eid     = cursor + N_NODES;                    // [E_TOTAL]
  int*   bsum    = eid + E_TOTAL;                       // [SCAN_BLOCKS]
  int*   boff    = bsum + SCAN_BLOCKS + 16;             // [SCAN_BLOCKS]
  ushort* Bp     = (ushort*)x1;                         // aliases x1 (dead then)

  float* out0   = (float*)d_out;                        // [N][30]
  float* alpha1 = out0 + (size_t)N_NODES * 30;          // [E_TOTAL][8]
  float* alpha2 = alpha1 + (size_t)E_TOTAL * 8;         // [E_TOTAL]

  hipMemsetAsync(deg, 0, N_NODES * sizeof(int), stream);
  hipMemsetAsync(cursor, 0, N_NODES * sizeof(int), stream);

  k_prepB<<<(KSTEPS * 4 * 128 + 255) / 256, 256, 0, stream>>>(w_res, w1, Bp);
  k_gemm_mfma<<<(N_NODES + 63) / 64, 256, 0, stream>>>(x, Bp, b_res, Hres, Hatt);
  k_attn1<<<(N_NODES * HEADS + 255) / 256, 256, 0, stream>>>(Hatt, att_src1, att_dst1,
                                                             a_src1, a_dst1);
  k_degree<<<(E_TOTAL + 255) / 256, 256, 0, stream>>>(ei, deg);
  k_bsum<<<SCAN_BLOCKS, 256, 0, stream>>>(deg, bsum);
  k_bscan<<<1, 256, 0, stream>>>(bsum, boff);
  k_blocal<<<SCAN_BLOCKS, 256, 0, stream>>>(deg, boff, rowptr);
  k_fill<<<(E_TOTAL + 255) / 256, 256, 0, stream>>>(ei, rowptr, cursor, eid);
  k_layer1<<<(N_NODES + 3) / 4, 256, 0, stream>>>(ei, rowptr, eid, Hres, Hatt,
                                                  a_src1, a_dst1, b1, x1, alpha1);
  k_layer2prep<<<(N_NODES + 3) / 4, 256, 0, stream>>>(x1, w2, att_src2, att_dst2,
                                                      h2b, a_src2, a_dst2);
  k_layer2<<<(N_NODES + 3) / 4, 256, 0, stream>>>(ei, rowptr, eid, h2b, a_src2,
                                                  a_dst2, b2, out0, alpha2);
}

// Round 6
// 581.233 us; speedup vs baseline: 2.2665x; 1.1079x over previous
//
#include <hip/hip_runtime.h>
#include <hip/hip_bf16.h>

#define N_NODES 50000
#define NUM_FEAT 2000
#define HEADS 8
#define HID 8
#define NUM_CLASSES 30
#define NUM_EDGES 1600000
#define E_TOTAL (NUM_EDGES + N_NODES)
#define KSTEPS 63   // ceil(2000/32)
#define SCAN_BLOCKS ((N_NODES + 255) / 256)   // 196

typedef __attribute__((ext_vector_type(8))) short short8;
typedef __attribute__((ext_vector_type(4))) float f32x4;

typedef __attribute__((address_space(1))) const unsigned int gu32;
typedef __attribute__((address_space(3))) unsigned int lu32;

__device__ __forceinline__ void gload_lds16(const void* g, void* l) {
  __builtin_amdgcn_global_load_lds((gu32*)g, (lu32*)l, 16, 0, 0);
}

__device__ __forceinline__ ushort f2bf(float f) {
  __hip_bfloat16 b = __float2bfloat16(f);
  return *reinterpret_cast<ushort*>(&b);
}

__device__ __forceinline__ float bf2f(ushort u) {
  unsigned int x = ((unsigned int)u) << 16;
  union { unsigned int i; float f; } c; c.i = x;
  return c.f;
}

__device__ __forceinline__ short8 cvt8(float4 a, float4 b) {
  union { short8 v; ushort u[8]; } p;
  p.u[0] = f2bf(a.x); p.u[1] = f2bf(a.y); p.u[2] = f2bf(a.z); p.u[3] = f2bf(a.w);
  p.u[4] = f2bf(b.x); p.u[5] = f2bf(b.y); p.u[6] = f2bf(b.z); p.u[7] = f2bf(b.w);
  return p.v;
}

// ---- pack weights into per-K-step LDS fragment image: [t][kg][col][j] -------
__global__ void k_prepB(const float* __restrict__ Wres, const float* __restrict__ W1,
                        ushort* __restrict__ Bp) {
  int i = blockIdx.x * 256 + threadIdx.x;          // i = (t*4+kg)*128 + col
  if (i >= KSTEPS * 4 * 128) return;
  int col = i & 127;
  int kbase = (i >> 7) * 8;
  const float* W = (col < 64) ? Wres : W1;
  int c = col & 63;
  union { short8 v; ushort u[8]; } p;
#pragma unroll
  for (int j = 0; j < 8; ++j) {
    int k = kbase + j;
    p.u[j] = f2bf(k < NUM_FEAT ? W[(size_t)k * 64 + c] : 0.f);
  }
  *(short8*)&Bp[(size_t)i * 8] = p.v;
}

// ---- MFMA GEMM: Hres[n][0:64] = x@w_res + b_res (f32); Hatt = x@w1 (bf16) ---
__global__ __launch_bounds__(256) void k_gemm_mfma(const float* __restrict__ X,
    const ushort* __restrict__ Bp, const float* __restrict__ brs,
    float* __restrict__ Hres, ushort* __restrict__ Hatt) {
  __shared__ ushort ldsB[2][4096];                 // [buf][kg*128+col][8]
  const int tid = threadIdx.x;
  const int lane = tid & 63, wid = tid >> 6;
  const int lg = lane >> 4, lr = lane & 15;
  const int m0 = blockIdx.x * 64;

  int rowg = m0 + wid * 16 + lr;
  rowg = rowg < N_NODES ? rowg : N_NODES - 1;
  const float* axp = X + (size_t)rowg * NUM_FEAT + lg * 8;

  f32x4 acc[8] = {};
  float4 a0, a1, na0, na1;
  const float4 fz = make_float4(0.f, 0.f, 0.f, 0.f);

  auto loadA = [&](int t, float4& r0, float4& r1) {
    int k0 = t * 32 + lg * 8;
    if (k0 < NUM_FEAT) {
      r0 = *(const float4*)(axp + t * 32);
      r1 = *(const float4*)(axp + t * 32 + 4);
    } else { r0 = fz; r1 = fz; }
  };
  auto stageB = [&](int t, int buf) {
    const ushort* g0 = Bp + (size_t)t * 4096 + (size_t)(wid * 64 + lane) * 8;
    gload_lds16(g0, &ldsB[buf][(size_t)(wid * 64) * 8]);
    gload_lds16(g0 + 2048, &ldsB[buf][(size_t)(256 + wid * 64) * 8]);
  };

  stageB(0, 0);
  loadA(0, a0, a1);
  __syncthreads();

  for (int t = 0; t < KSTEPS - 1; ++t) {
    const int cur = t & 1, nxt = cur ^ 1;
    stageB(t + 1, nxt);
    short8 fb[8];
#pragma unroll
    for (int n = 0; n < 8; ++n)
      fb[n] = *(const short8*)&ldsB[cur][(size_t)(lg * 128 + n * 16 + lr) * 8];
    loadA(t + 1, na0, na1);
    short8 fa = cvt8(a0, a1);
#pragma unroll
    for (int n = 0; n < 8; ++n)
      acc[n] = __builtin_amdgcn_mfma_f32_16x16x32_bf16(fa, fb[n], acc[n], 0, 0, 0);
    a0 = na0; a1 = na1;
    __syncthreads();
  }
  {
    const int cur = (KSTEPS - 1) & 1;
    short8 fb[8];
#pragma unroll
    for (int n = 0; n < 8; ++n)
      fb[n] = *(const short8*)&ldsB[cur][(size_t)(lg * 128 + n * 16 + lr) * 8];
    short8 fa = cvt8(a0, a1);
#pragma unroll
    for (int n = 0; n < 8; ++n)
      acc[n] = __builtin_amdgcn_mfma_f32_16x16x32_bf16(fa, fb[n], acc[n], 0, 0, 0);
  }

  // epilogue: C/D map col=lane&15, row=(lane>>4)*4+i  [m89-verified]
#pragma unroll
  for (int n = 0; n < 8; ++n) {
    int col = n * 16 + lr;
    if (col < 64) {
      float badd = brs[col];
#pragma unroll
      for (int i = 0; i < 4; ++i) {
        int row = m0 + wid * 16 + lg * 4 + i;
        if (row < N_NODES) Hres[(size_t)row * 64 + col] = acc[n][i] + badd;
      }
    } else {
#pragma unroll
      for (int i = 0; i < 4; ++i) {
        int row = m0 + wid * 16 + lg * 4 + i;
        if (row < N_NODES) Hatt[(size_t)row * 64 + (col - 64)] = f2bf(acc[n][i]);
      }
    }
  }
}

// ---------------- per-node attention logits for layer 1 ---------------------
__global__ void k_attn1(const ushort* __restrict__ Hatt, const float* __restrict__ att_src,
                        const float* __restrict__ att_dst, float* __restrict__ a_src,
                        float* __restrict__ a_dst) {
  int i = blockIdx.x * blockDim.x + threadIdx.x;  // i = n*8 + h
  if (i >= N_NODES * HEADS) return;
  int h = i & 7;
  const ushort* hp = &Hatt[(size_t)(i >> 3) * 64 + h * 8];
  float s = 0.f, d = 0.f;
#pragma unroll
  for (int c = 0; c < 8; ++c) {
    float v = bf2f(hp[c]);
    s = fmaf(v, att_src[h * 8 + c], s);
    d = fmaf(v, att_dst[h * 8 + c], d);
  }
  a_src[i] = s; a_dst[i] = d;
}

// ---------------- CSR build (by dst): degree, 3-phase scan, fill ------------
__global__ void k_degree(const int* __restrict__ ei, int* __restrict__ deg) {
  int e = blockIdx.x * blockDim.x + threadIdx.x;
  if (e >= E_TOTAL) return;
  int d = e < NUM_EDGES ? ei[NUM_EDGES + e] : e - NUM_EDGES;
  atomicAdd(&deg[d], 1);
}

__global__ __launch_bounds__(256) void k_bsum(const int* __restrict__ deg,
                                              int* __restrict__ bsum) {
  __shared__ int sm[256];
  int t = threadIdx.x, i = blockIdx.x * 256 + t;
  sm[t] = (i < N_NODES) ? deg[i] : 0;
  __syncthreads();
  for (int off = 128; off > 0; off >>= 1) {
    if (t < off) sm[t] += sm[t + off];
    __syncthreads();
  }
  if (t == 0) bsum[blockIdx.x] = sm[0];
}

__global__ __launch_bounds__(256) void k_bscan(const int* __restrict__ bsum,
                                               int* __restrict__ boff) {
  __shared__ int sm[256];
  int t = threadIdx.x;
  int own = (t < SCAN_BLOCKS) ? bsum[t] : 0;
  sm[t] = own;
  __syncthreads();
  for (int off = 1; off < 256; off <<= 1) {
    int add = (t >= off) ? sm[t - off] : 0;
    __syncthreads();
    sm[t] += add;
    __syncthreads();
  }
  if (t < SCAN_BLOCKS) boff[t] = sm[t] - own;   // exclusive
}

__global__ __launch_bounds__(256) void k_blocal(const int* __restrict__ deg,
    const int* __restrict__ boff, int* __restrict__ rowptr) {
  __shared__ int sm[256];
  int t = threadIdx.x, b = blockIdx.x, i = b * 256 + t;
  int v = (i < N_NODES) ? deg[i] : 0;
  sm[t] = v;
  __syncthreads();
  for (int off = 1; off < 256; off <<= 1) {
    int add = (t >= off) ? sm[t - off] : 0;
    __syncthreads();
    sm[t] += add;
    __syncthreads();
  }
  if (i < N_NODES) rowptr[i + 1] = boff[b] + sm[t];
  if (i == 0) rowptr[0] = 0;
}

// fill writes (edge_id, src) pairs -> consumers skip the ei[e] indirection
__global__ void k_fill(const int* __restrict__ ei, const int* __restrict__ rowptr,
                       int* __restrict__ cursor, int2* __restrict__ eid2) {
  int e = blockIdx.x * blockDim.x + threadIdx.x;
  if (e >= E_TOTAL) return;
  int s, d;
  if (e < NUM_EDGES) { s = ei[e]; d = ei[NUM_EDGES + e]; }
  else { s = d = e - NUM_EDGES; }
  int pos = atomicAdd(&cursor[d], 1);
  eid2[rowptr[d] + pos] = make_int2(e, s);
}

// ---------------- layer-1 aggregation: one wave per node, lane = (head*8+c) --
__global__ __launch_bounds__(256) void k_layer1(const int2* __restrict__ eid2,
    const int* __restrict__ rowptr,
    const float* __restrict__ Hres, const ushort* __restrict__ Hatt,
    const float* __restrict__ a_src, const float* __restrict__ a_dst,
    const float* __restrict__ b1, float* __restrict__ x1,
    float* __restrict__ inv1) {
  int wave = threadIdx.x >> 6, lane = threadIdx.x & 63;
  int n = blockIdx.x * 4 + wave;
  if (n >= N_NODES) return;
  int hd = lane >> 3;
  float adn = a_dst[n * 8 + hd];
  int start = rowptr[n], end = rowptr[n + 1];
  float denom = 0.f, msg = 0.f;
  // 8 edges in flight per iteration: independent gather chains (2-deep now)
  for (int p = start; p < end; p += 8) {
    int s8[8];
#pragma unroll
    for (int i = 0; i < 8; ++i) {
      int idx = p + i; idx = idx < end ? idx : end - 1;
      s8[i] = eid2[idx].y;
    }
    float av[8];
    ushort hu[8];
#pragma unroll
    for (int i = 0; i < 8; ++i) {
      av[i] = a_src[s8[i] * 8 + hd];
      hu[i] = Hatt[(size_t)s8[i] * 64 + lane];
    }
#pragma unroll
    for (int i = 0; i < 8; ++i) {
      if (p + i < end) {
        float sc = av[i] + adn;
        sc = sc > 0.f ? sc : 0.2f * sc;
        float ev = __expf(sc);
        denom += ev;
        msg = fmaf(ev, bf2f(hu[i]), msg);
      }
    }
  }
  float invd = 1.f / (denom + 1e-16f);
  float h1v = msg * invd + b1[lane];
  float x1v = h1v + Hres[(size_t)n * 64 + lane];   // residual part
  x1v = x1v > 0.f ? x1v : __expf(x1v) - 1.f;       // elu
  x1[(size_t)n * 64 + lane] = x1v;
  if ((lane & 7) == 0) inv1[n * 8 + hd] = invd;    // per (dst, head) normalizer
}

// ---------------- alpha1: edge-order, fully coalesced -----------------------
__global__ __launch_bounds__(256) void k_alpha1(const int* __restrict__ ei,
    const float* __restrict__ a_src, const float* __restrict__ a_dst,
    const float* __restrict__ inv1, float* __restrict__ alpha1) {
  int i = blockIdx.x * 256 + threadIdx.x;          // i = e*8 + h
  if (i >= E_TOTAL * 8) return;
  int e = i >> 3, h = i & 7;
  int s, d;
  if (e < NUM_EDGES) { s = ei[e]; d = ei[NUM_EDGES + e]; }
  else { s = d = e - NUM_EDGES; }
  float sc = a_src[s * 8 + h] + a_dst[d * 8 + h];
  sc = sc > 0.f ? sc : 0.2f * sc;
  alpha1[i] = __expf(sc) * inv1[d * 8 + h];
}

// ---------------- layer-2 prep: h2 = x1 @ w2 (+attn logits), bf16 table -----
__global__ __launch_bounds__(256) void k_layer2prep(const float* __restrict__ x1,
    const float* __restrict__ w2, const float* __restrict__ att_src2,
    const float* __restrict__ att_dst2, ushort* __restrict__ h2b,
    float* __restrict__ a_src2, float* __restrict__ a_dst2) {
  __shared__ float w2s[64 * 30];
  for (int i = threadIdx.x; i < 64 * 30; i += 256) w2s[i] = w2[i];
  __syncthreads();
  int wave = threadIdx.x >> 6, lane = threadIdx.x & 63;
  int n = blockIdx.x * 4 + wave;
  if (n >= N_NODES) return;
  float acc = 0.f;
  const float* xr = &x1[(size_t)n * 64];
  if (lane < 30) {
#pragma unroll 8
    for (int k = 0; k < 64; ++k) acc = fmaf(xr[k], w2s[k * 30 + lane], acc);
  }
  float as = (lane < 30) ? acc * att_src2[lane] : 0.f;
  float ad = (lane < 30) ? acc * att_dst2[lane] : 0.f;
  for (int off = 1; off < 64; off <<= 1) {
    as += __shfl_xor(as, off);
    ad += __shfl_xor(ad, off);
  }
  if (lane == 0) { a_src2[n] = as; a_dst2[n] = ad; }
  if (lane < 32) h2b[(size_t)n * 32 + lane] = (lane < 30) ? f2bf(acc) : (ushort)0;
}

// ---------------- layer-2 aggregation + elu + log_softmax -------------------
__global__ __launch_bounds__(256) void k_layer2(const int2* __restrict__ eid2,
    const int* __restrict__ rowptr,
    const ushort* __restrict__ h2b, const float* __restrict__ a_src2,
    const float* __restrict__ a_dst2, const float* __restrict__ b2,
    float* __restrict__ out0, float* __restrict__ inv2) {
  int wave = threadIdx.x >> 6, lane = threadIdx.x & 63;
  int n = blockIdx.x * 4 + wave;
  if (n >= N_NODES) return;
  float adn = a_dst2[n];
  int start = rowptr[n], end = rowptr[n + 1];
  int half = lane >> 5, cls = lane & 31;
  float denom = 0.f, msg = 0.f;
  // 2x unroll: 4 edges in flight (2 per 32-lane half)
  for (int p = start; p < end; p += 4) {
    int idx0 = p + half, idx1 = p + 2 + half;
    bool vl0 = idx0 < end, vl1 = idx1 < end;
    int s0 = eid2[vl0 ? idx0 : end - 1].y;
    int s1 = eid2[vl1 ? idx1 : end - 1].y;
    float as0 = a_src2[s0], as1 = a_src2[s1];
    ushort hv0 = h2b[(size_t)s0 * 32 + cls];
    ushort hv1 = h2b[(size_t)s1 * 32 + cls];
    if (vl0) {
      float sc = as0 + adn;
      sc = sc > 0.f ? sc : 0.2f * sc;
      float ev = __expf(sc);
      denom += ev;
      msg = fmaf(ev, bf2f(hv0), msg);
    }
    if (vl1) {
      float sc = as1 + adn;
      sc = sc > 0.f ? sc : 0.2f * sc;
      float ev = __expf(sc);
      denom += ev;
      msg = fmaf(ev, bf2f(hv1), msg);
    }
  }
  denom += __shfl_xor(denom, 32);
  msg   += __shfl_xor(msg, 32);
  float invd = 1.f / (denom + 1e-16f);
  bool act = lane < 30;
  float o = act ? msg * invd + b2[lane] : 0.f;
  float x2 = o > 0.f ? o : __expf(o) - 1.f;
  float mv = act ? x2 : -1e30f;
  for (int off = 1; off < 64; off <<= 1) mv = fmaxf(mv, __shfl_xor(mv, off));
  float ex = act ? __expf(x2 - mv) : 0.f;
  for (int off = 1; off < 64; off <<= 1) ex += __shfl_xor(ex, off);
  if (act) out0[(size_t)n * 30 + lane] = x2 - mv - __logf(ex);
  if (lane == 0) inv2[n] = invd;
}

// ---------------- alpha2: edge-order, fully coalesced -----------------------
__global__ __launch_bounds__(256) void k_alpha2(const int* __restrict__ ei,
    const float* __restrict__ a_src2, const float* __restrict__ a_dst2,
    const float* __restrict__ inv2, float* __restrict__ alpha2) {
  int e = blockIdx.x * 256 + threadIdx.x;
  if (e >= E_TOTAL) return;
  int s, d;
  if (e < NUM_EDGES) { s = ei[e]; d = ei[NUM_EDGES + e]; }
  else { s = d = e - NUM_EDGES; }
  float sc = a_src2[s] + a_dst2[d];
  sc = sc > 0.f ? sc : 0.2f * sc;
  alpha2[e] = __expf(sc) * inv2[d];
}

extern "C" void kernel_launch(void* const* d_in, const int* in_sizes, int n_in,
                              void* d_out, int out_size, void* d_ws, size_t ws_size,
                              hipStream_t stream) {
  const float* x        = (const float*)d_in[0];
  const int*   ei       = (const int*)d_in[1];
  const float* w_res    = (const float*)d_in[2];
  const float* b_res    = (const float*)d_in[3];
  const float* w1       = (const float*)d_in[4];
  const float* att_src1 = (const float*)d_in[5];
  const float* att_dst1 = (const float*)d_in[6];
  const float* b1       = (const float*)d_in[7];
  const float* w2       = (const float*)d_in[8];
  const float* att_src2 = (const float*)d_in[9];
  const float* att_dst2 = (const float*)d_in[10];
  const float* b2       = (const float*)d_in[11];

  float* ws = (float*)d_ws;
  float* Hres    = ws;                                  // [N][64] f32
  float* x1      = Hres + (size_t)N_NODES * 64;         // [N][64] f32
  float* a_src1  = x1 + (size_t)N_NODES * 64;           // [N][8]
  float* a_dst1  = a_src1 + (size_t)N_NODES * 8;        // [N][8]
  float* inv1    = a_dst1 + (size_t)N_NODES * 8;        // [N][8]
  float* a_src2  = inv1 + (size_t)N_NODES * 8;          // [N]
  float* a_dst2  = a_src2 + N_NODES;                    // [N]
  float* inv2    = a_dst2 + N_NODES;                    // [N]
  ushort* Hatt   = (ushort*)(inv2 + N_NODES);           // [N][64] bf16
  ushort* h2b    = Hatt + (size_t)N_NODES * 64;         // [N][32] bf16
  int*   deg     = (int*)(h2b + (size_t)N_NODES * 32);  // [N]
  int*   rowptr  = deg + N_NODES;                       // [N+1] (pad)
  int*   cursor  = rowptr + N_NODES + 16;               // [N]
  int*   bsum    = cursor + N_NODES;                    // [SCAN_BLOCKS]
  int*   boff    = bsum + SCAN_BLOCKS + 16;             // [SCAN_BLOCKS]
  ushort* Bp     = (ushort*)x1;                         // aliases x1 (dead then)

  float* out0   = (float*)d_out;                        // [N][30]
  float* alpha1 = out0 + (size_t)N_NODES * 30;          // [E_TOTAL][8]
  float* alpha2 = alpha1 + (size_t)E_TOTAL * 8;         // [E_TOTAL]
  // eid2 aliases the alpha1 output region (13.2 MB < 52.8 MB); alpha1 is
  // written only AFTER the last eid2 reader (k_layer2) completes.
  int2*  eid2   = (int2*)alpha1;

  hipMemsetAsync(deg, 0, N_NODES * sizeof(int), stream);
  hipMemsetAsync(cursor, 0, N_NODES * sizeof(int), stream);

  k_prepB<<<(KSTEPS * 4 * 128 + 255) / 256, 256, 0, stream>>>(w_res, w1, Bp);
  k_gemm_mfma<<<(N_NODES + 63) / 64, 256, 0, stream>>>(x, Bp, b_res, Hres, Hatt);
  k_attn1<<<(N_NODES * HEADS + 255) / 256, 256, 0, stream>>>(Hatt, att_src1, att_dst1,
                                                             a_src1, a_dst1);
  k_degree<<<(E_TOTAL + 255) / 256, 256, 0, stream>>>(ei, deg);
  k_bsum<<<SCAN_BLOCKS, 256, 0, stream>>>(deg, bsum);
  k_bscan<<<1, 256, 0, stream>>>(bsum, boff);
  k_blocal<<<SCAN_BLOCKS, 256, 0, stream>>>(deg, boff, rowptr);
  k_fill<<<(E_TOTAL + 255) / 256, 256, 0, stream>>>(ei, rowptr, cursor, eid2);
  k_layer1<<<(N_NODES + 3) / 4, 256, 0, stream>>>(eid2, rowptr, Hres, Hatt,
                                                  a_src1, a_dst1, b1, x1, inv1);
  k_layer2prep<<<(N_NODES + 3) / 4, 256, 0, stream>>>(x1, w2, att_src2, att_dst2,
                                                      h2b, a_src2, a_dst2);
  k_layer2<<<(N_NODES + 3) / 4, 256, 0, stream>>>(eid2, rowptr, h2b, a_src2,
                                                  a_dst2, b2, out0, inv2);
  k_alpha1<<<(E_TOTAL * 8 + 255) / 256, 256, 0, stream>>>(ei, a_src1, a_dst1,
                                                          inv1, alpha1);
  k_alpha2<<<(E_TOTAL + 255) / 256, 256, 0, stream>>>(ei, a_src2, a_dst2,
                                                      inv2, alpha2);
}